// Round 11
// baseline (223.653 us; speedup 1.0000x reference)
//
#include <hip/hip_runtime.h>
#include <cstdint>
#include <math.h>

// ---------- types ----------
typedef __attribute__((ext_vector_type(8))) short bf16x8;   // MFMA A/B operand (4 VGPRs)
typedef __attribute__((ext_vector_type(4))) float f32x4;    // MFMA C/D operand
typedef __attribute__((ext_vector_type(4))) unsigned short u16x4;

__device__ __forceinline__ unsigned short f2bf(float f) {
  union { float f; unsigned int u; } c; c.f = f;
  unsigned int u = c.u;
  return (unsigned short)((u + 0x7FFFu + ((u >> 16) & 1u)) >> 16);  // RNE
}
__device__ __forceinline__ float bf2f(unsigned short u) {
  return __uint_as_float(((unsigned int)u) << 16);
}

// pack hi16(a) | hi16(b)<<16 via v_perm_b32 (1 VALU op; trunc-to-bf16)
__device__ __forceinline__ unsigned int pack_trunc(float a, float b) {
  return __builtin_amdgcn_perm(__float_as_uint(b), __float_as_uint(a), 0x07060302u);
}

__device__ __forceinline__ float fmax3(float a, float b, float c) {
  return fmaxf(fmaxf(a, b), c);  // clang fuses to v_max3_f32
}

__device__ __forceinline__ void gload_lds16(const void* g, void* l) {
  __builtin_amdgcn_global_load_lds(
      (const __attribute__((address_space(1))) unsigned int*)g,
      (__attribute__((address_space(3))) unsigned int*)l, 16, 0, 0);
}

// ---------- fp32 -> bf16 convert (x and out_w in one launch) ----------
__global__ __launch_bounds__(256)
void k_convert2(const float* __restrict__ inA, unsigned short* __restrict__ outA,
                const float* __restrict__ inB, unsigned short* __restrict__ outB,
                int n4A, int n4B) {
  int i = blockIdx.x * 256 + threadIdx.x;
  if (i < n4A) {
    float4 v = ((const float4*)inA)[i];
    u16x4 o;
    o.x = f2bf(v.x); o.y = f2bf(v.y); o.z = f2bf(v.z); o.w = f2bf(v.w);
    ((u16x4*)outA)[i] = o;
  } else {
    int j = i - n4A;
    if (j >= n4B) return;
    float4 v = ((const float4*)inB)[j];
    u16x4 o;
    o.x = f2bf(v.x); o.y = f2bf(v.y); o.z = f2bf(v.z); o.w = f2bf(v.w);
    ((u16x4*)outB)[j] = o;
  }
}

// ---------- fp32 [1024][1024] -> bf16 [1024][1024] transpose, 4 matrices ----------
__global__ __launch_bounds__(256)
void k_transpose4(const float* __restrict__ w0, const float* __restrict__ w1,
                  const float* __restrict__ w2, const float* __restrict__ w3,
                  unsigned short* __restrict__ o012, unsigned short* __restrict__ o3) {
  __shared__ float t[32][33];
  const float* in = blockIdx.z == 0 ? w0 : blockIdx.z == 1 ? w1 : blockIdx.z == 2 ? w2 : w3;
  unsigned short* out = blockIdx.z < 3 ? o012 + (size_t)blockIdx.z * 1048576 : o3;
  int c0 = blockIdx.x * 32, r0 = blockIdx.y * 32;
  int tx = threadIdx.x & 31, ty = threadIdx.x >> 5;  // 32 x 8
#pragma unroll
  for (int rr = ty; rr < 32; rr += 8) t[rr][tx] = in[(size_t)(r0 + rr) * 1024 + c0 + tx];
  __syncthreads();
#pragma unroll
  for (int cc = ty; cc < 32; cc += 8)
    out[(size_t)(c0 + cc) * 1024 + r0 + tx] = f2bf(t[tx][cc]);
}

// ---------- bf16 GEMM 128x128, dbuf + 1 barrier/K-step (T3-min) ----------
template <int OUTBF>
__global__ __launch_bounds__(256)
void k_gemm_bt(const unsigned short* __restrict__ A, const unsigned short* __restrict__ BT,
               void* __restrict__ C, int M, int N, int K) {
  __shared__ __align__(16) unsigned short As[2][128 * 32];
  __shared__ __align__(16) unsigned short Bs[2][128 * 32];
  const int tid = threadIdx.x;
  const int wid = tid >> 6, lane = tid & 63;
  const int l16 = lane & 15, krow = lane >> 4;
  const int m0 = blockIdx.x * 128, n0 = blockIdx.y * 128;
  const int wr = wid >> 1, wc = wid & 1;  // 2x2 waves, 64x64 each

  f32x4 acc[4][4] = {};

  auto stageG = [&](int buf, int k0) {
#pragma unroll
    for (int j = 0; j < 2; j++) {
      int f = j * 256 + tid;
      gload_lds16(A  + (size_t)(m0 + (f >> 2)) * K + k0 + (f & 3) * 8,
                  (char*)As[buf] + (size_t)(j * 256 + wid * 64) * 16);
      gload_lds16(BT + (size_t)(n0 + (f >> 2)) * K + k0 + (f & 3) * 8,
                  (char*)Bs[buf] + (size_t)(j * 256 + wid * 64) * 16);
    }
  };
  auto comp = [&](int buf) {
    bf16x8 a[4], b[4];
#pragma unroll
    for (int i = 0; i < 4; i++) {
      a[i] = *(const bf16x8*)&As[buf][(wr * 64 + i * 16 + l16) * 32 + krow * 8];
      b[i] = *(const bf16x8*)&Bs[buf][(wc * 64 + i * 16 + l16) * 32 + krow * 8];
    }
#pragma unroll
    for (int mi = 0; mi < 4; mi++)
#pragma unroll
      for (int ni = 0; ni < 4; ni++)
        acc[mi][ni] = __builtin_amdgcn_mfma_f32_16x16x32_bf16(a[mi], b[ni], acc[mi][ni], 0, 0, 0);
  };

  stageG(0, 0);
  __syncthreads();
  for (int k0 = 0; k0 < K; k0 += 64) {
    if (k0 + 32 < K) stageG(1, k0 + 32);
    comp(0);
    __syncthreads();
    if (k0 + 64 < K) stageG(0, k0 + 64);
    comp(1);
    __syncthreads();
  }

#pragma unroll
  for (int mi = 0; mi < 4; mi++)
#pragma unroll
    for (int ni = 0; ni < 4; ni++)
#pragma unroll
      for (int r = 0; r < 4; r++) {
        int row = m0 + wr * 64 + mi * 16 + krow * 4 + r;
        int col = n0 + wc * 64 + ni * 16 + l16;
        float v = acc[mi][ni][r];
        if (OUTBF) ((unsigned short*)C)[(size_t)row * N + col] = f2bf(v);
        else       ((float*)C)[(size_t)row * N + col] = v;
      }
}

// ---------- bf16 GEMM 128x64, dbuf + 1 barrier/K-step ----------
template <int OUTBF>
__global__ __launch_bounds__(256)
void k_gemm_bt_n64(const unsigned short* __restrict__ A, const unsigned short* __restrict__ BT,
                   void* __restrict__ C, int M, int N, int K) {
  __shared__ __align__(16) unsigned short As[2][128 * 32];
  __shared__ __align__(16) unsigned short Bs[2][64 * 32];
  const int tid = threadIdx.x;
  const int wid = tid >> 6, lane = tid & 63;
  const int l16 = lane & 15, krow = lane >> 4;
  const int m0 = blockIdx.x * 128, n0 = blockIdx.y * 64;
  const int wr = wid >> 1, wc = wid & 1;  // 2x2 waves, 64x32 each

  f32x4 acc[4][2] = {};

  auto stageG = [&](int buf, int k0) {
#pragma unroll
    for (int j = 0; j < 2; j++) {
      int f = j * 256 + tid;
      gload_lds16(A + (size_t)(m0 + (f >> 2)) * K + k0 + (f & 3) * 8,
                  (char*)As[buf] + (size_t)(j * 256 + wid * 64) * 16);
    }
    gload_lds16(BT + (size_t)(n0 + (tid >> 2)) * K + k0 + (tid & 3) * 8,
                (char*)Bs[buf] + (size_t)(wid * 64) * 16);
  };
  auto comp = [&](int buf) {
    bf16x8 a[4], b[2];
#pragma unroll
    for (int i = 0; i < 4; i++)
      a[i] = *(const bf16x8*)&As[buf][(wr * 64 + i * 16 + l16) * 32 + krow * 8];
#pragma unroll
    for (int i = 0; i < 2; i++)
      b[i] = *(const bf16x8*)&Bs[buf][(wc * 32 + i * 16 + l16) * 32 + krow * 8];
#pragma unroll
    for (int mi = 0; mi < 4; mi++)
#pragma unroll
      for (int ni = 0; ni < 2; ni++)
        acc[mi][ni] = __builtin_amdgcn_mfma_f32_16x16x32_bf16(a[mi], b[ni], acc[mi][ni], 0, 0, 0);
  };

  stageG(0, 0);
  __syncthreads();
  for (int k0 = 0; k0 < K; k0 += 64) {
    if (k0 + 32 < K) stageG(1, k0 + 32);
    comp(0);
    __syncthreads();
    if (k0 + 64 < K) stageG(0, k0 + 64);
    comp(1);
    __syncthreads();
  }

#pragma unroll
  for (int mi = 0; mi < 4; mi++)
#pragma unroll
    for (int ni = 0; ni < 2; ni++)
#pragma unroll
      for (int r = 0; r < 4; r++) {
        int row = m0 + wr * 64 + mi * 16 + krow * 4 + r;
        int col = n0 + wc * 32 + ni * 16 + l16;
        float v = acc[mi][ni][r];
        if (OUTBF) ((unsigned short*)C)[(size_t)row * N + col] = f2bf(v);
        else       ((float*)C)[(size_t)row * N + col] = v;
      }
}

// ---------- V transpose (tiled): Vt[h*64+d][s] = QKV[s][2048 + h*64 + d] ----------
__global__ __launch_bounds__(256)
void k_vt(const unsigned short* __restrict__ QKV, unsigned short* __restrict__ Vt) {
  __shared__ unsigned short t[64 * 65];
  const int tid = threadIdx.x;
  const int s0 = blockIdx.x * 64, c0 = blockIdx.y * 64;
  const int sl = tid >> 3, ch = tid & 7;  // 32 rows x 8 chunks per pass
#pragma unroll
  for (int half = 0; half < 2; half++) {
    int s = half * 32 + sl;
    bf16x8 v = *(const bf16x8*)&QKV[(size_t)(s0 + s) * 3072 + 2048 + c0 + ch * 8];
#pragma unroll
    for (int k = 0; k < 8; k++) t[s * 65 + ch * 8 + k] = (unsigned short)v[k];
  }
  __syncthreads();
  const int cl = tid >> 2, si = (tid & 3) * 16;
  bf16x8 o0, o1;
#pragma unroll
  for (int i = 0; i < 8; i++) o0[i] = (short)t[(si + i) * 65 + cl];
#pragma unroll
  for (int i = 0; i < 8; i++) o1[i] = (short)t[(si + 8 + i) * 65 + cl];
  *(bf16x8*)&Vt[(size_t)(c0 + cl) * 4096 + s0 + si] = o0;
  *(bf16x8*)&Vt[(size_t)(c0 + cl) * 4096 + s0 + si + 8] = o1;
}

// ---------- flash attention, split-KV x2, 32 q/wave ----------
// 4 waves/WG (256 thr), 128 q-rows/WG, 32 q-rows/wave, 32 KV tiles of 64 per WG.
// grid 1024 (16 heads x 2 halves x 32 qb) -> 4 WG/CU (32 KB LDS) = 16 waves/CU.
// 32 q/wave HALVES LDS-read traffic per unit work vs 16 q/wave (the R10 wall).
// Emits normalized bf16 partial O + per-row score s = m + log2(l); k_comb merges.
__global__ __launch_bounds__(256, 4)
void k_flash(const unsigned short* __restrict__ QKV, const unsigned short* __restrict__ Vt,
             unsigned short* __restrict__ Opart, float* __restrict__ sml) {
  // shorts: dbuf 2 x (K 4096 | V 4096) = 32 KB
  __shared__ __align__(16) unsigned short LDS[16384];
  const int tid = threadIdx.x, wid = tid >> 6, lane = tid & 63;
  const int l16 = lane & 15, krow = lane >> 4;
  const int bid = blockIdx.x;
  const int swz = (bid & 7) * 128 + (bid >> 3);   // 1024 % 8 == 0 -> bijective
  const int head = swz >> 6;          // 0..15
  const int half = (swz >> 5) & 1;    // KV half
  const int qb = swz & 31;            // 0..31
  const int kv0 = half * 32;
  const float SC = 0.125f * 1.44269504089f;       // scale into log2 domain

  // Q fragments (B-operand of swapped QK^T): lane holds q-row l16 (per mi)
  bf16x8 qf[2][2];
#pragma unroll
  for (int mi = 0; mi < 2; mi++)
#pragma unroll
    for (int ks = 0; ks < 2; ks++) {
      int row = qb * 128 + wid * 32 + mi * 16 + l16;
      qf[mi][ks] = *(const bf16x8*)&QKV[(size_t)row * 3072 + head * 64 + ks * 32 + krow * 8];
    }

  f32x4 oaccT[2][4] = {};   // O^T tiles [mi][di]; col=q(l16), row=d(krow*4+r)
  float mrun[2] = {-INFINITY, -INFINITY};  // uniform across the 4 krow-lanes of a q
  float lrun[2] = {0.f, 0.f};              // PER-LANE partials (reduced in epilogue)

  auto stage = [&](int buf, int kt) {
#pragma unroll
    for (int j = 0; j < 2; j++) {
      int f = j * 256 + tid, row = f >> 3, sch = (f & 7) ^ (row & 7);  // pre-swizzled source
      gload_lds16(QKV + (size_t)(kt * 64 + row) * 3072 + 1024 + head * 64 + sch * 8,
                  (char*)LDS + buf * 16384 + (j * 256 + wid * 64) * 16);
      gload_lds16(Vt + (size_t)(head * 64 + row) * 4096 + kt * 64 + sch * 8,
                  (char*)LDS + buf * 16384 + 8192 + (j * 256 + wid * 64) * 16);
    }
  };

  auto body = [&](int buf) {
    const unsigned short* Ks = LDS + buf * 8192;
    const char* VsB = (const char*)(LDS + buf * 8192 + 4096);

    // swapped QK^T: sacc[mi][ni] = S^T tile; lane owns q=l16, kv=ni*16+krow*4+r
    f32x4 sacc[2][4] = {};
    __builtin_amdgcn_s_setprio(1);
#pragma unroll
    for (int ks = 0; ks < 2; ks++)
#pragma unroll
      for (int ni = 0; ni < 4; ni++) {
        int row = ni * 16 + l16;
        bf16x8 kf = *(const bf16x8*)&Ks[row * 64 + (((ks * 4 + krow) ^ (row & 7)) << 3)];
#pragma unroll
        for (int mi = 0; mi < 2; mi++)
          sacc[mi][ni] = __builtin_amdgcn_mfma_f32_16x16x32_bf16(kf, qf[mi][ks], sacc[mi][ni], 0, 0, 0);
      }
    __builtin_amdgcn_s_setprio(0);

    // per-lane partial max over this lane's 16 kv values, per mi (raw domain)
    float pm[2];
#pragma unroll
    for (int mi = 0; mi < 2; mi++) {
      float a = fmax3(sacc[mi][0][0], sacc[mi][0][1], sacc[mi][0][2]);
      a = fmax3(a, sacc[mi][0][3], sacc[mi][1][0]);
      a = fmax3(a, sacc[mi][1][1], sacc[mi][1][2]);
      a = fmax3(a, sacc[mi][1][3], sacc[mi][2][0]);
      a = fmax3(a, sacc[mi][2][1], sacc[mi][2][2]);
      a = fmax3(a, sacc[mi][2][3], sacc[mi][3][0]);
      a = fmax3(a, sacc[mi][3][1], sacc[mi][3][2]);
      pm[mi] = fmaxf(a, sacc[mi][3][3]);
    }

    // defer-max: cross-lane reduce + rescale only when some lane's partial
    // exceeds the running max by > 8 (log2 domain)
    if (__ballot((__builtin_fmaf(pm[0], SC, -mrun[0]) > 8.f) ||
                 (__builtin_fmaf(pm[1], SC, -mrun[1]) > 8.f))) {
#pragma unroll
      for (int mi = 0; mi < 2; mi++) {
        float a = pm[mi];
        a = fmaxf(a, __shfl_xor(a, 16));
        a = fmaxf(a, __shfl_xor(a, 32));      // uniform per q now
        float mnew = fmaxf(mrun[mi], a * SC);
        float al = __builtin_amdgcn_exp2f(mrun[mi] - mnew);  // per-lane q: no broadcast
        lrun[mi] *= al;
        mrun[mi] = mnew;
#pragma unroll
        for (int di = 0; di < 4; di++)
#pragma unroll
          for (int r = 0; r < 4; r++) oaccT[mi][di][r] *= al;
      }
    }

    // P = exp2(s*SC - m); per-lane partial row-sum
#pragma unroll
    for (int mi = 0; mi < 2; mi++)
#pragma unroll
      for (int ni = 0; ni < 4; ni++)
#pragma unroll
        for (int r = 0; r < 4; r++) {
          float p = __builtin_amdgcn_exp2f(__builtin_fmaf(sacc[mi][ni][r], SC, -mrun[mi]));
          sacc[mi][ni][r] = p;
          lrun[mi] += p;
        }

    // B-frags: P^T packed from this lane's OWN sacc under k-slot perm pi:
    //   pi(ks,krow,j) = (2ks + (j>>2))*16 + krow*4 + (j&3)
    union PB { unsigned int w[4]; bf16x8 v; };
    PB pb[2][2];
#pragma unroll
    for (int mi = 0; mi < 2; mi++)
#pragma unroll
      for (int ks = 0; ks < 2; ks++) {
        pb[mi][ks].w[0] = pack_trunc(sacc[mi][2 * ks][0],     sacc[mi][2 * ks][1]);
        pb[mi][ks].w[1] = pack_trunc(sacc[mi][2 * ks][2],     sacc[mi][2 * ks][3]);
        pb[mi][ks].w[2] = pack_trunc(sacc[mi][2 * ks + 1][0], sacc[mi][2 * ks + 1][1]);
        pb[mi][ks].w[3] = pack_trunc(sacc[mi][2 * ks + 1][2], sacc[mi][2 * ks + 1][3]);
      }

    // O^T += V^T P^T: A-frag under same pi = two b64 reads from swizzled Vs,
    // SHARED across both mi tiles (this is the 2x LDS-read amortization)
    __builtin_amdgcn_s_setprio(1);
#pragma unroll
    for (int ks = 0; ks < 2; ks++)
#pragma unroll
      for (int di = 0; di < 4; di++) {
        int row = di * 16 + l16;
        int base = row * 128 + ((krow & 1) << 3);
        union PB av;
        *(uint2*)&av.w[0] = *(const uint2*)(VsB + base + (((ks * 4 + (krow >> 1)) ^ (row & 7)) << 4));
        *(uint2*)&av.w[2] = *(const uint2*)(VsB + base + (((ks * 4 + 2 + (krow >> 1)) ^ (row & 7)) << 4));
#pragma unroll
        for (int mi = 0; mi < 2; mi++)
          oaccT[mi][di] = __builtin_amdgcn_mfma_f32_16x16x32_bf16(av.v, pb[mi][ks].v, oaccT[mi][di], 0, 0, 0);
      }
    __builtin_amdgcn_s_setprio(0);
  };

  stage(0, kv0);
  __syncthreads();
  for (int kt = 0; kt < 32; kt += 2) {
    stage(1, kv0 + kt + 1);
    body(0);
    __syncthreads();           // buf1 staged+drained; all reads of buf0 done
    if (kt + 2 < 32) stage(0, kv0 + kt + 2);
    body(1);
    __syncthreads();
  }

  // epilogue: reduce per-lane l partials, normalized bf16 partial O + score
#pragma unroll
  for (int mi = 0; mi < 2; mi++) {
    float lr = lrun[mi];
    lr += __shfl_xor(lr, 16);
    lr += __shfl_xor(lr, 32);
    float li = 1.0f / lr;
    int row = qb * 128 + wid * 32 + mi * 16 + l16;
#pragma unroll
    for (int di = 0; di < 4; di++) {
      uint2 w;
      w.x = (unsigned)f2bf(oaccT[mi][di][0] * li) | ((unsigned)f2bf(oaccT[mi][di][1] * li) << 16);
      w.y = (unsigned)f2bf(oaccT[mi][di][2] * li) | ((unsigned)f2bf(oaccT[mi][di][3] * li) << 16);
      *(uint2*)&Opart[(size_t)(half * 4096 + row) * 1024 + head * 64 + di * 16 + krow * 4] = w;
    }
    if (krow == 0)
      sml[(size_t)(half * 16 + head) * 4096 + row] = mrun[mi] + __builtin_amdgcn_logf(lr);
  }
}

// ---------- combine the two KV-half partials -> ctx bf16 ----------
__global__ __launch_bounds__(256)
void k_comb(const unsigned short* __restrict__ Opart, const float* __restrict__ sml,
            unsigned short* __restrict__ ctx) {
  const int row = blockIdx.x, tid = threadIdx.x;
  const int col = tid * 4;
  const int h = col >> 6;
  float s0 = sml[(size_t)h * 4096 + row];
  float s1 = sml[(size_t)(16 + h) * 4096 + row];
  float M = fmaxf(s0, s1);
  float w0 = __builtin_amdgcn_exp2f(s0 - M), w1 = __builtin_amdgcn_exp2f(s1 - M);
  float inv = 1.0f / (w0 + w1);
  w0 *= inv; w1 *= inv;
  u16x4 a = *(const u16x4*)&Opart[(size_t)row * 1024 + col];
  u16x4 b = *(const u16x4*)&Opart[(size_t)(4096 + row) * 1024 + col];
  u16x4 o;
#pragma unroll
  for (int j = 0; j < 4; j++)
    o[j] = f2bf(bf2f(a[j]) * w0 + bf2f(b[j]) * w1);
  *(u16x4*)&ctx[(size_t)row * 1024 + col] = o;
}

// ---------- LN(base + add): emits fp32 + bf16 copies ----------
__global__ __launch_bounds__(256)
void k_ln_res(const float* __restrict__ base, const float* __restrict__ add,
              const float* __restrict__ g, const float* __restrict__ bb,
              float* __restrict__ outf, unsigned short* __restrict__ outb) {
  const int r = blockIdx.x, tid = threadIdx.x;
  float4 v = ((const float4*)(base + (size_t)r * 1024))[tid];
  {
    float4 w = ((const float4*)(add + (size_t)r * 1024))[tid];
    v.x += w.x; v.y += w.y; v.z += w.z; v.w += w.w;
  }
  float s1 = v.x + v.y + v.z + v.w;
  float s2 = v.x * v.x + v.y * v.y + v.z * v.z + v.w * v.w;
#pragma unroll
  for (int off = 32; off >= 1; off >>= 1) { s1 += __shfl_xor(s1, off); s2 += __shfl_xor(s2, off); }
  __shared__ float red[8];
  if ((tid & 63) == 0) { red[tid >> 6] = s1; red[4 + (tid >> 6)] = s2; }
  __syncthreads();
  s1 = red[0] + red[1] + red[2] + red[3];
  s2 = red[4] + red[5] + red[6] + red[7];
  const float mu = s1 * (1.0f / 1024.0f);
  const float var = s2 * (1.0f / 1024.0f) - mu * mu;
  const float rs = rsqrtf(var + 1e-5f);
  float4 gv = ((const float4*)g)[tid];
  float4 bv = ((const float4*)bb)[tid];
  float4 y;
  y.x = (v.x - mu) * rs * gv.x + bv.x;
  y.y = (v.y - mu) * rs * gv.y + bv.y;
  y.z = (v.z - mu) * rs * gv.z + bv.z;
  y.w = (v.w - mu) * rs * gv.w + bv.w;
  ((float4*)(outf + (size_t)r * 1024))[tid] = y;
  u16x4 o;
  o.x = f2bf(y.x); o.y = f2bf(y.y); o.z = f2bf(y.z); o.w = f2bf(y.w);
  ((u16x4*)(outb + (size_t)r * 1024))[tid] = o;
}

// ---------- relu(LN(lin + out_b + mha)) -> fp32 out ----------
__global__ __launch_bounds__(256)
void k_ln2(const float* __restrict__ lin, const float* __restrict__ mha,
           const float* __restrict__ ob, const float* __restrict__ g,
           const float* __restrict__ bb, float* __restrict__ out) {
  const int r = blockIdx.x, tid = threadIdx.x;
  float4 v = ((const float4*)(lin + (size_t)r * 1024))[tid];
  {
    float4 w = ((const float4*)(mha + (size_t)r * 1024))[tid];
    float4 o = ((const float4*)ob)[tid];
    v.x += w.x + o.x; v.y += w.y + o.y; v.z += w.z + o.z; v.w += w.w + o.w;
  }
  float s1 = v.x + v.y + v.z + v.w;
  float s2 = v.x * v.x + v.y * v.y + v.z * v.z + v.w * v.w;
#pragma unroll
  for (int off = 32; off >= 1; off >>= 1) { s1 += __shfl_xor(s1, off); s2 += __shfl_xor(s2, off); }
  __shared__ float red[8];
  if ((tid & 63) == 0) { red[tid >> 6] = s1; red[4 + (tid >> 6)] = s2; }
  __syncthreads();
  s1 = red[0] + red[1] + red[2] + red[3];
  s2 = red[4] + red[5] + red[6] + red[7];
  const float mu = s1 * (1.0f / 1024.0f);
  const float var = s2 * (1.0f / 1024.0f) - mu * mu;
  const float rs = rsqrtf(var + 1e-5f);
  float4 gv = ((const float4*)g)[tid];
  float4 bv = ((const float4*)bb)[tid];
  float4 y;
  y.x = fmaxf(0.f, (v.x - mu) * rs * gv.x + bv.x);
  y.y = fmaxf(0.f, (v.y - mu) * rs * gv.y + bv.y);
  y.z = fmaxf(0.f, (v.z - mu) * rs * gv.z + bv.z);
  y.w = fmaxf(0.f, (v.w - mu) * rs * gv.w + bv.w);
  ((float4*)(out + (size_t)r * 1024))[tid] = y;
}

// ---------- launch ----------
extern "C" void kernel_launch(void* const* d_in, const int* in_sizes, int n_in,
                              void* d_out, int out_size, void* d_ws, size_t ws_size,
                              hipStream_t stream) {
  (void)in_sizes; (void)n_in; (void)out_size; (void)ws_size;
  const float* x     = (const float*)d_in[0];
  const float* Wq    = (const float*)d_in[1];
  const float* Wk    = (const float*)d_in[2];
  const float* Wv    = (const float*)d_in[3];
  const float* Wo    = (const float*)d_in[4];
  const float* out_w = (const float*)d_in[5];
  const float* out_b = (const float*)d_in[6];
  const float* g1    = (const float*)d_in[7];
  const float* b1    = (const float*)d_in[8];
  const float* g2    = (const float*)d_in[9];
  const float* b2    = (const float*)d_in[10];
  float* out = (float*)d_out;

  // workspace layout (aliased; 60 MB total, liveness-checked)
  const size_t MB = 1ull << 20;
  char* ws = (char*)d_ws;
  unsigned short* xb    = (unsigned short*)(ws + 0);        // [4096][1024] bf16   (dead after GEMM1)
  unsigned short* WqkvT = (unsigned short*)(ws + 8 * MB);   // [3072][1024] bf16   (dead after GEMM1)
  unsigned short* Opart = (unsigned short*)(ws + 0);        // [2][4096][1024] bf16 (over xb/WqkvT; dead after comb)
  unsigned short* OwB   = (unsigned short*)(ws + 16 * MB);  // out_w bf16 [1024][1024]
  unsigned short* QKV   = (unsigned short*)(ws + 18 * MB);  // [4096][3072] bf16   (dead after attn)
  unsigned short* Vt    = (unsigned short*)(ws + 42 * MB);  // [1024][4096] bf16   (dead after attn)
  unsigned short* ctx   = (unsigned short*)(ws + 50 * MB);  // [4096][1024] bf16   (dead after GEMM2)
  unsigned short* WoT   = (unsigned short*)(ws + 58 * MB);  // W_o^T bf16
  float*          proj  = (float*)(ws + 0);                 // [4096][1024] f32 (over Opart, after comb)
  float*          mhaF  = (float*)(ws + 18 * MB);           // [4096][1024] f32 (over QKV head)
  unsigned short* mhaB  = (unsigned short*)(ws + 34 * MB);  // [4096][1024] bf16 (over QKV tail)
  float*          lin   = (float*)(ws + 42 * MB);           // [4096][1024] f32 (over Vt/ctx)
  float*          sml   = (float*)d_out;                    // [2][16][4096] f32 scratch (ln2 overwrites)

  k_convert2<<<5120, 256, 0, stream>>>(x, xb, out_w, OwB, 1048576, 262144);
  k_transpose4<<<dim3(32, 32, 4), 256, 0, stream>>>(Wq, Wk, Wv, Wo, WqkvT, WoT);

  k_gemm_bt<1><<<dim3(32, 24), 256, 0, stream>>>(xb, WqkvT, QKV, 4096, 3072, 1024);
  k_vt<<<dim3(64, 16), 256, 0, stream>>>(QKV, Vt);
  k_flash<<<1024, 256, 0, stream>>>(QKV, Vt, Opart, sml);
  k_comb<<<4096, 256, 0, stream>>>(Opart, sml, ctx);
  k_gemm_bt_n64<0><<<dim3(32, 16), 256, 0, stream>>>(ctx, WoT, proj, 4096, 1024, 1024);
  k_ln_res<<<4096, 256, 0, stream>>>(x, proj, g1, b1, mhaF, mhaB);
  k_gemm_bt_n64<0><<<dim3(32, 16), 256, 0, stream>>>(mhaB, OwB, lin, 4096, 1024, 1024);
  k_ln2<<<4096, 256, 0, stream>>>(lin, mhaF, out_b, g2, b2, out);
}

// Round 12
// 197.678 us; speedup vs baseline: 1.1314x; 1.1314x over previous
//
#include <hip/hip_runtime.h>
#include <cstdint>
#include <math.h>

// ---------- types ----------
typedef __attribute__((ext_vector_type(8))) short bf16x8;   // MFMA A/B operand (4 VGPRs)
typedef __attribute__((ext_vector_type(4))) float f32x4;    // MFMA C/D operand
typedef __attribute__((ext_vector_type(4))) unsigned short u16x4;

__device__ __forceinline__ unsigned short f2bf(float f) {
  union { float f; unsigned int u; } c; c.f = f;
  unsigned int u = c.u;
  return (unsigned short)((u + 0x7FFFu + ((u >> 16) & 1u)) >> 16);  // RNE
}
__device__ __forceinline__ float bf2f(unsigned short u) {
  return __uint_as_float(((unsigned int)u) << 16);
}

// pack hi16(a) | hi16(b)<<16 via v_perm_b32 (1 VALU op; trunc-to-bf16)
__device__ __forceinline__ unsigned int pack_trunc(float a, float b) {
  return __builtin_amdgcn_perm(__float_as_uint(b), __float_as_uint(a), 0x07060302u);
}

__device__ __forceinline__ float fmax3(float a, float b, float c) {
  return fmaxf(fmaxf(a, b), c);  // clang fuses to v_max3_f32
}

__device__ __forceinline__ void gload_lds16(const void* g, void* l) {
  __builtin_amdgcn_global_load_lds(
      (const __attribute__((address_space(1))) unsigned int*)g,
      (__attribute__((address_space(3))) unsigned int*)l, 16, 0, 0);
}

// ---------- prep: weight transposes (blocks 0..4095) + fp32->bf16 converts ----------
__global__ __launch_bounds__(256)
void k_prep(const float* __restrict__ x, unsigned short* __restrict__ xb,
            const float* __restrict__ out_w, unsigned short* __restrict__ OwB,
            const float* __restrict__ w0, const float* __restrict__ w1,
            const float* __restrict__ w2, const float* __restrict__ w3,
            unsigned short* __restrict__ o012, unsigned short* __restrict__ o3) {
  __shared__ float t[32][33];
  const int b = blockIdx.x;
  if (b < 4096) {
    const int m = b >> 10, rem = b & 1023;
    const float* in = m == 0 ? w0 : m == 1 ? w1 : m == 2 ? w2 : w3;
    unsigned short* out = m < 3 ? o012 + (size_t)m * 1048576 : o3;
    const int r0 = (rem >> 5) << 5, c0 = (rem & 31) << 5;
    const int tx = threadIdx.x & 31, ty = threadIdx.x >> 5;  // 32 x 8
#pragma unroll
    for (int rr = ty; rr < 32; rr += 8) t[rr][tx] = in[(size_t)(r0 + rr) * 1024 + c0 + tx];
    __syncthreads();
#pragma unroll
    for (int cc = ty; cc < 32; cc += 8)
      out[(size_t)(c0 + cc) * 1024 + r0 + tx] = f2bf(t[tx][cc]);
  } else {
    int i = (b - 4096) * 256 + threadIdx.x;
    const float* in;
    unsigned short* out;
    if (i < 1048576) { in = x; out = xb; }
    else { i -= 1048576; if (i >= 262144) return; in = out_w; out = OwB; }
    float4 v = ((const float4*)in)[i];
    u16x4 o;
    o.x = f2bf(v.x); o.y = f2bf(v.y); o.z = f2bf(v.z); o.w = f2bf(v.w);
    ((u16x4*)out)[i] = o;
  }
}

// ---------- bf16 GEMM 128x128, dbuf + 1 barrier/K-step (T3-min) ----------
template <int OUTBF>
__global__ __launch_bounds__(256)
void k_gemm_bt(const unsigned short* __restrict__ A, const unsigned short* __restrict__ BT,
               void* __restrict__ C, int M, int N, int K) {
  __shared__ __align__(16) unsigned short As[2][128 * 32];
  __shared__ __align__(16) unsigned short Bs[2][128 * 32];
  const int tid = threadIdx.x;
  const int wid = tid >> 6, lane = tid & 63;
  const int l16 = lane & 15, krow = lane >> 4;
  const int m0 = blockIdx.x * 128, n0 = blockIdx.y * 128;
  const int wr = wid >> 1, wc = wid & 1;  // 2x2 waves, 64x64 each

  f32x4 acc[4][4] = {};

  auto stageG = [&](int buf, int k0) {
#pragma unroll
    for (int j = 0; j < 2; j++) {
      int f = j * 256 + tid;
      gload_lds16(A  + (size_t)(m0 + (f >> 2)) * K + k0 + (f & 3) * 8,
                  (char*)As[buf] + (size_t)(j * 256 + wid * 64) * 16);
      gload_lds16(BT + (size_t)(n0 + (f >> 2)) * K + k0 + (f & 3) * 8,
                  (char*)Bs[buf] + (size_t)(j * 256 + wid * 64) * 16);
    }
  };
  auto comp = [&](int buf) {
    bf16x8 a[4], b[4];
#pragma unroll
    for (int i = 0; i < 4; i++) {
      a[i] = *(const bf16x8*)&As[buf][(wr * 64 + i * 16 + l16) * 32 + krow * 8];
      b[i] = *(const bf16x8*)&Bs[buf][(wc * 64 + i * 16 + l16) * 32 + krow * 8];
    }
#pragma unroll
    for (int mi = 0; mi < 4; mi++)
#pragma unroll
      for (int ni = 0; ni < 4; ni++)
        acc[mi][ni] = __builtin_amdgcn_mfma_f32_16x16x32_bf16(a[mi], b[ni], acc[mi][ni], 0, 0, 0);
  };

  stageG(0, 0);
  __syncthreads();
  for (int k0 = 0; k0 < K; k0 += 64) {
    if (k0 + 32 < K) stageG(1, k0 + 32);
    comp(0);
    __syncthreads();
    if (k0 + 64 < K) stageG(0, k0 + 64);
    comp(1);
    __syncthreads();
  }

#pragma unroll
  for (int mi = 0; mi < 4; mi++)
#pragma unroll
    for (int ni = 0; ni < 4; ni++)
#pragma unroll
      for (int r = 0; r < 4; r++) {
        int row = m0 + wr * 64 + mi * 16 + krow * 4 + r;
        int col = n0 + wc * 64 + ni * 16 + l16;
        float v = acc[mi][ni][r];
        if (OUTBF) ((unsigned short*)C)[(size_t)row * N + col] = f2bf(v);
        else       ((float*)C)[(size_t)row * N + col] = v;
      }
}

// ---------- bf16 GEMM 128x64, dbuf + 1 barrier/K-step ----------
template <int OUTBF>
__global__ __launch_bounds__(256)
void k_gemm_bt_n64(const unsigned short* __restrict__ A, const unsigned short* __restrict__ BT,
                   void* __restrict__ C, int M, int N, int K) {
  __shared__ __align__(16) unsigned short As[2][128 * 32];
  __shared__ __align__(16) unsigned short Bs[2][64 * 32];
  const int tid = threadIdx.x;
  const int wid = tid >> 6, lane = tid & 63;
  const int l16 = lane & 15, krow = lane >> 4;
  const int m0 = blockIdx.x * 128, n0 = blockIdx.y * 64;
  const int wr = wid >> 1, wc = wid & 1;  // 2x2 waves, 64x32 each

  f32x4 acc[4][2] = {};

  auto stageG = [&](int buf, int k0) {
#pragma unroll
    for (int j = 0; j < 2; j++) {
      int f = j * 256 + tid;
      gload_lds16(A + (size_t)(m0 + (f >> 2)) * K + k0 + (f & 3) * 8,
                  (char*)As[buf] + (size_t)(j * 256 + wid * 64) * 16);
    }
    gload_lds16(BT + (size_t)(n0 + (tid >> 2)) * K + k0 + (tid & 3) * 8,
                (char*)Bs[buf] + (size_t)(wid * 64) * 16);
  };
  auto comp = [&](int buf) {
    bf16x8 a[4], b[2];
#pragma unroll
    for (int i = 0; i < 4; i++)
      a[i] = *(const bf16x8*)&As[buf][(wr * 64 + i * 16 + l16) * 32 + krow * 8];
#pragma unroll
    for (int i = 0; i < 2; i++)
      b[i] = *(const bf16x8*)&Bs[buf][(wc * 32 + i * 16 + l16) * 32 + krow * 8];
#pragma unroll
    for (int mi = 0; mi < 4; mi++)
#pragma unroll
      for (int ni = 0; ni < 2; ni++)
        acc[mi][ni] = __builtin_amdgcn_mfma_f32_16x16x32_bf16(a[mi], b[ni], acc[mi][ni], 0, 0, 0);
  };

  stageG(0, 0);
  __syncthreads();
  for (int k0 = 0; k0 < K; k0 += 64) {
    if (k0 + 32 < K) stageG(1, k0 + 32);
    comp(0);
    __syncthreads();
    if (k0 + 64 < K) stageG(0, k0 + 64);
    comp(1);
    __syncthreads();
  }

#pragma unroll
  for (int mi = 0; mi < 4; mi++)
#pragma unroll
    for (int ni = 0; ni < 2; ni++)
#pragma unroll
      for (int r = 0; r < 4; r++) {
        int row = m0 + wr * 64 + mi * 16 + krow * 4 + r;
        int col = n0 + wc * 32 + ni * 16 + l16;
        float v = acc[mi][ni][r];
        if (OUTBF) ((unsigned short*)C)[(size_t)row * N + col] = f2bf(v);
        else       ((float*)C)[(size_t)row * N + col] = v;
      }
}

// ---------- V transpose (tiled): Vt[h*64+d][s] = QKV[s][2048 + h*64 + d] ----------
__global__ __launch_bounds__(256)
void k_vt(const unsigned short* __restrict__ QKV, unsigned short* __restrict__ Vt) {
  __shared__ unsigned short t[64 * 65];
  const int tid = threadIdx.x;
  const int s0 = blockIdx.x * 64, c0 = blockIdx.y * 64;
  const int sl = tid >> 3, ch = tid & 7;  // 32 rows x 8 chunks per pass
#pragma unroll
  for (int half = 0; half < 2; half++) {
    int s = half * 32 + sl;
    bf16x8 v = *(const bf16x8*)&QKV[(size_t)(s0 + s) * 3072 + 2048 + c0 + ch * 8];
#pragma unroll
    for (int k = 0; k < 8; k++) t[s * 65 + ch * 8 + k] = (unsigned short)v[k];
  }
  __syncthreads();
  const int cl = tid >> 2, si = (tid & 3) * 16;
  bf16x8 o0, o1;
#pragma unroll
  for (int i = 0; i < 8; i++) o0[i] = (short)t[(si + i) * 65 + cl];
#pragma unroll
  for (int i = 0; i < 8; i++) o1[i] = (short)t[(si + 8 + i) * 65 + cl];
  *(bf16x8*)&Vt[(size_t)(c0 + cl) * 4096 + s0 + si] = o0;
  *(bf16x8*)&Vt[(size_t)(c0 + cl) * 4096 + s0 + si + 8] = o1;
}

// ---------- flash attention (R10 config: best measured) ----------
// 8 waves/WG (512 thr), 128 q-rows/WG, 16 q-rows/wave, grid 512 (16 heads x 32 qb).
// LDS 32 KB dbuf K+V -> 2 WG/CU = 16 waves/CU. Swapped QK^T -> lane-local softmax
// (per-lane partial max, defer-max; per-lane partial l reduced in epilogue).
// PV: P^T B-frag = lane's own packed sacc under k-slot perm pi; V A-frag = two
// ds_read_b64 under the same pi.
__global__ __launch_bounds__(512)
void k_flash(const unsigned short* __restrict__ QKV, const unsigned short* __restrict__ Vt,
             unsigned short* __restrict__ ctx) {
  // shorts: dbuf 2 x (K 4096 | V 4096) = 32 KB
  __shared__ __align__(16) unsigned short LDS[16384];
  const int tid = threadIdx.x, wid = tid >> 6, lane = tid & 63;
  const int l16 = lane & 15, krow = lane >> 4;
  const int bid = blockIdx.x;
  const int swz = (bid & 7) * 64 + (bid >> 3);    // 512 % 8 == 0 -> bijective
  const int head = swz >> 5, qb = swz & 31;       // 2 heads per XCD (K/V/Q ~3MB < 4MB L2)
  const float SC = 0.125f * 1.44269504089f;       // scale into log2 domain

  // Q fragments (B-operand of swapped QK^T): lane holds q-row l16, d = ks*32+krow*8..+7
  bf16x8 qf[2];
#pragma unroll
  for (int ks = 0; ks < 2; ks++) {
    int row = qb * 128 + wid * 16 + l16;
    qf[ks] = *(const bf16x8*)&QKV[(size_t)row * 3072 + head * 64 + ks * 32 + krow * 8];
  }

  f32x4 oaccT[4] = {};      // O^T tiles [di]; col=q(l16), row=d(krow*4+r)
  float mrun = -INFINITY;   // uniform across the 4 krow-lanes of a q
  float lrun = 0.f;         // PER-LANE partial (reduced in epilogue)

  // one pass stages the whole 16 KB tile: 512 thr x (16B K + 16B V)
  auto stage = [&](int buf, int kt) {
    int row = tid >> 3, ch = tid & 7, sch = ch ^ (row & 7);  // pre-swizzled source
    gload_lds16(QKV + (size_t)(kt * 64 + row) * 3072 + 1024 + head * 64 + sch * 8,
                (char*)LDS + buf * 16384 + wid * 1024);          // + lane*16 by HW
    gload_lds16(Vt + (size_t)(head * 64 + row) * 4096 + kt * 64 + sch * 8,
                (char*)LDS + buf * 16384 + 8192 + wid * 1024);   // + lane*16 by HW
  };

  auto body = [&](int buf) {
    const unsigned short* Ks = LDS + buf * 8192;
    const char* VsB = (const char*)(LDS + buf * 8192 + 4096);

    // swapped QK^T: sacc[ni] = S^T tile [kv 16][q 16]; lane owns q=l16, kv=ni*16+krow*4+r
    f32x4 sacc[4] = {};
    __builtin_amdgcn_s_setprio(1);
#pragma unroll
    for (int ks = 0; ks < 2; ks++)
#pragma unroll
      for (int ni = 0; ni < 4; ni++) {
        int row = ni * 16 + l16;
        bf16x8 kf = *(const bf16x8*)&Ks[row * 64 + (((ks * 4 + krow) ^ (row & 7)) << 3)];
        sacc[ni] = __builtin_amdgcn_mfma_f32_16x16x32_bf16(kf, qf[ks], sacc[ni], 0, 0, 0);
      }
    __builtin_amdgcn_s_setprio(0);

    // per-lane partial max over this lane's 16 kv values (raw domain)
    float a = fmax3(sacc[0][0], sacc[0][1], sacc[0][2]);
    a = fmax3(a, sacc[0][3], sacc[1][0]);
    a = fmax3(a, sacc[1][1], sacc[1][2]);
    a = fmax3(a, sacc[1][3], sacc[2][0]);
    a = fmax3(a, sacc[2][1], sacc[2][2]);
    a = fmax3(a, sacc[2][3], sacc[3][0]);
    a = fmax3(a, sacc[3][1], sacc[3][2]);
    a = fmaxf(a, sacc[3][3]);

    // defer-max: cross-lane reduce + rescale only when some lane's partial
    // exceeds the running max by > 8 (log2 domain)
    if (__ballot(__builtin_fmaf(a, SC, -mrun) > 8.f)) {
      a = fmaxf(a, __shfl_xor(a, 16));
      a = fmaxf(a, __shfl_xor(a, 32));      // uniform per q now
      float mnew = fmaxf(mrun, a * SC);
      float al = __builtin_amdgcn_exp2f(mrun - mnew);
      lrun *= al;
      mrun = mnew;
#pragma unroll
      for (int di = 0; di < 4; di++)
#pragma unroll
        for (int r = 0; r < 4; r++) oaccT[di][r] *= al;
    }

    // P = exp2(s*SC - m); per-lane partial row-sum
#pragma unroll
    for (int ni = 0; ni < 4; ni++)
#pragma unroll
      for (int r = 0; r < 4; r++) {
        float p = __builtin_amdgcn_exp2f(__builtin_fmaf(sacc[ni][r], SC, -mrun));
        sacc[ni][r] = p;
        lrun += p;
      }

    // B-frags: P^T packed from this lane's OWN sacc under k-slot perm pi:
    //   pi(ks,krow,j) = (2ks + (j>>2))*16 + krow*4 + (j&3)
    union PB { unsigned int w[4]; bf16x8 v; };
    PB pb[2];
#pragma unroll
    for (int ks = 0; ks < 2; ks++) {
      pb[ks].w[0] = pack_trunc(sacc[2 * ks][0],     sacc[2 * ks][1]);
      pb[ks].w[1] = pack_trunc(sacc[2 * ks][2],     sacc[2 * ks][3]);
      pb[ks].w[2] = pack_trunc(sacc[2 * ks + 1][0], sacc[2 * ks + 1][1]);
      pb[ks].w[3] = pack_trunc(sacc[2 * ks + 1][2], sacc[2 * ks + 1][3]);
    }

    // O^T += V^T P^T: A-frag under same pi = two b64 reads from swizzled Vs
    __builtin_amdgcn_s_setprio(1);
#pragma unroll
    for (int ks = 0; ks < 2; ks++)
#pragma unroll
      for (int di = 0; di < 4; di++) {
        int row = di * 16 + l16;
        int base = row * 128 + ((krow & 1) << 3);
        union PB av;
        *(uint2*)&av.w[0] = *(const uint2*)(VsB + base + (((ks * 4 + (krow >> 1)) ^ (row & 7)) << 4));
        *(uint2*)&av.w[2] = *(const uint2*)(VsB + base + (((ks * 4 + 2 + (krow >> 1)) ^ (row & 7)) << 4));
        oaccT[di] = __builtin_amdgcn_mfma_f32_16x16x32_bf16(av.v, pb[ks].v, oaccT[di], 0, 0, 0);
      }
    __builtin_amdgcn_s_setprio(0);
  };

  stage(0, 0);
  __syncthreads();
  for (int kt = 0; kt < 64; kt += 2) {
    stage(1, kt + 1);
    body(0);
    __syncthreads();           // buf1 staged+drained; all reads of buf0 done
    if (kt + 2 < 64) stage(0, kt + 2);
    body(1);
    __syncthreads();
  }

  // epilogue: reduce per-lane l partials across the 4 krow-lanes of each q,
  // then per-lane normalize + 8B packed stores
  float lr = lrun;
  lr += __shfl_xor(lr, 16);
  lr += __shfl_xor(lr, 32);
  float li = 1.0f / lr;
  int row = qb * 128 + wid * 16 + l16;
#pragma unroll
  for (int di = 0; di < 4; di++) {
    uint2 w;
    w.x = (unsigned)f2bf(oaccT[di][0] * li) | ((unsigned)f2bf(oaccT[di][1] * li) << 16);
    w.y = (unsigned)f2bf(oaccT[di][2] * li) | ((unsigned)f2bf(oaccT[di][3] * li) << 16);
    *(uint2*)&ctx[(size_t)row * 1024 + head * 64 + di * 16 + krow * 4] = w;
  }
}

// ---------- LN(x + proj_bf16) -> bf16 only ----------
__global__ __launch_bounds__(256)
void k_ln_res(const float* __restrict__ base, const unsigned short* __restrict__ add,
              const float* __restrict__ g, const float* __restrict__ bb,
              unsigned short* __restrict__ outb) {
  const int r = blockIdx.x, tid = threadIdx.x;
  float4 v = ((const float4*)(base + (size_t)r * 1024))[tid];
  {
    u16x4 w = ((const u16x4*)(add + (size_t)r * 1024))[tid];
    v.x += bf2f(w.x); v.y += bf2f(w.y); v.z += bf2f(w.z); v.w += bf2f(w.w);
  }
  float s1 = v.x + v.y + v.z + v.w;
  float s2 = v.x * v.x + v.y * v.y + v.z * v.z + v.w * v.w;
#pragma unroll
  for (int off = 32; off >= 1; off >>= 1) { s1 += __shfl_xor(s1, off); s2 += __shfl_xor(s2, off); }
  __shared__ float red[8];
  if ((tid & 63) == 0) { red[tid >> 6] = s1; red[4 + (tid >> 6)] = s2; }
  __syncthreads();
  s1 = red[0] + red[1] + red[2] + red[3];
  s2 = red[4] + red[5] + red[6] + red[7];
  const float mu = s1 * (1.0f / 1024.0f);
  const float var = s2 * (1.0f / 1024.0f) - mu * mu;
  const float rs = rsqrtf(var + 1e-5f);
  float4 gv = ((const float4*)g)[tid];
  float4 bv = ((const float4*)bb)[tid];
  u16x4 o;
  o.x = f2bf((v.x - mu) * rs * gv.x + bv.x);
  o.y = f2bf((v.y - mu) * rs * gv.y + bv.y);
  o.z = f2bf((v.z - mu) * rs * gv.z + bv.z);
  o.w = f2bf((v.w - mu) * rs * gv.w + bv.w);
  ((u16x4*)(outb + (size_t)r * 1024))[tid] = o;
}

// ---------- relu(LN(lin_bf16 + out_b + mha_bf16)) -> fp32 out ----------
__global__ __launch_bounds__(256)
void k_ln2(const unsigned short* __restrict__ lin, const unsigned short* __restrict__ mha,
           const float* __restrict__ ob, const float* __restrict__ g,
           const float* __restrict__ bb, float* __restrict__ out) {
  const int r = blockIdx.x, tid = threadIdx.x;
  float4 v;
  {
    u16x4 a = ((const u16x4*)(lin + (size_t)r * 1024))[tid];
    u16x4 w = ((const u16x4*)(mha + (size_t)r * 1024))[tid];
    float4 o = ((const float4*)ob)[tid];
    v.x = bf2f(a.x) + bf2f(w.x) + o.x;
    v.y = bf2f(a.y) + bf2f(w.y) + o.y;
    v.z = bf2f(a.z) + bf2f(w.z) + o.z;
    v.w = bf2f(a.w) + bf2f(w.w) + o.w;
  }
  float s1 = v.x + v.y + v.z + v.w;
  float s2 = v.x * v.x + v.y * v.y + v.z * v.z + v.w * v.w;
#pragma unroll
  for (int off = 32; off >= 1; off >>= 1) { s1 += __shfl_xor(s1, off); s2 += __shfl_xor(s2, off); }
  __shared__ float red[8];
  if ((tid & 63) == 0) { red[tid >> 6] = s1; red[4 + (tid >> 6)] = s2; }
  __syncthreads();
  s1 = red[0] + red[1] + red[2] + red[3];
  s2 = red[4] + red[5] + red[6] + red[7];
  const float mu = s1 * (1.0f / 1024.0f);
  const float var = s2 * (1.0f / 1024.0f) - mu * mu;
  const float rs = rsqrtf(var + 1e-5f);
  float4 gv = ((const float4*)g)[tid];
  float4 bv = ((const float4*)bb)[tid];
  float4 y;
  y.x = fmaxf(0.f, (v.x - mu) * rs * gv.x + bv.x);
  y.y = fmaxf(0.f, (v.y - mu) * rs * gv.y + bv.y);
  y.z = fmaxf(0.f, (v.z - mu) * rs * gv.z + bv.z);
  y.w = fmaxf(0.f, (v.w - mu) * rs * gv.w + bv.w);
  ((float4*)(out + (size_t)r * 1024))[tid] = y;
}

// ---------- launch ----------
extern "C" void kernel_launch(void* const* d_in, const int* in_sizes, int n_in,
                              void* d_out, int out_size, void* d_ws, size_t ws_size,
                              hipStream_t stream) {
  (void)in_sizes; (void)n_in; (void)out_size; (void)ws_size;
  const float* x     = (const float*)d_in[0];
  const float* Wq    = (const float*)d_in[1];
  const float* Wk    = (const float*)d_in[2];
  const float* Wv    = (const float*)d_in[3];
  const float* Wo    = (const float*)d_in[4];
  const float* out_w = (const float*)d_in[5];
  const float* out_b = (const float*)d_in[6];
  const float* g1    = (const float*)d_in[7];
  const float* b1    = (const float*)d_in[8];
  const float* g2    = (const float*)d_in[9];
  const float* b2    = (const float*)d_in[10];
  float* out = (float*)d_out;

  // workspace layout (aliased; 60 MB total, liveness-checked)
  const size_t MB = 1ull << 20;
  char* ws = (char*)d_ws;
  unsigned short* xb    = (unsigned short*)(ws + 0);        // [4096][1024] bf16   (dead after GEMM1)
  unsigned short* WqkvT = (unsigned short*)(ws + 8 * MB);   // [3072][1024] bf16   (dead after GEMM1)
  unsigned short* OwB   = (unsigned short*)(ws + 16 * MB);  // out_w bf16 [1024][1024]
  unsigned short* QKV   = (unsigned short*)(ws + 18 * MB);  // [4096][3072] bf16   (dead after attn)
  unsigned short* Vt    = (unsigned short*)(ws + 42 * MB);  // [1024][4096] bf16   (dead after attn)
  unsigned short* ctx   = (unsigned short*)(ws + 50 * MB);  // [4096][1024] bf16   (dead after GEMM2)
  unsigned short* WoT   = (unsigned short*)(ws + 58 * MB);  // W_o^T bf16
  unsigned short* proj  = (unsigned short*)(ws + 0);        // [4096][1024] bf16 (over xb)
  unsigned short* mhaB  = (unsigned short*)(ws + 34 * MB);  // [4096][1024] bf16 (over QKV tail)
  unsigned short* lin   = (unsigned short*)(ws + 42 * MB);  // [4096][1024] bf16 (over Vt)

  k_prep<<<9216, 256, 0, stream>>>(x, xb, out_w, OwB, Wq, Wk, Wv, Wo, WqkvT, WoT);

  k_gemm_bt<1><<<dim3(32, 24), 256, 0, stream>>>(xb, WqkvT, QKV, 4096, 3072, 1024);
  k_vt<<<dim3(64, 16), 256, 0, stream>>>(QKV, Vt);
  k_flash<<<512, 512, 0, stream>>>(QKV, Vt, ctx);
  k_gemm_bt_n64<1><<<dim3(32, 16), 256, 0, stream>>>(ctx, WoT, proj, 4096, 1024, 1024);
  k_ln_res<<<4096, 256, 0, stream>>>(x, proj, g1, b1, mhaB);
  k_gemm_bt_n64<1><<<dim3(32, 16), 256, 0, stream>>>(mhaB, OwB, lin, 4096, 1024, 1024);
  k_ln2<<<4096, 256, 0, stream>>>(lin, mhaB, out_b, g2, b2, out);
}

// Round 13
// 194.027 us; speedup vs baseline: 1.1527x; 1.0188x over previous
//
#include <hip/hip_runtime.h>
#include <cstdint>
#include <math.h>

// ---------- types ----------
typedef __attribute__((ext_vector_type(8))) short bf16x8;   // MFMA A/B operand (4 VGPRs)
typedef __attribute__((ext_vector_type(4))) float f32x4;    // MFMA C/D operand
typedef __attribute__((ext_vector_type(4))) unsigned short u16x4;

__device__ __forceinline__ unsigned short f2bf(float f) {
  union { float f; unsigned int u; } c; c.f = f;
  unsigned int u = c.u;
  return (unsigned short)((u + 0x7FFFu + ((u >> 16) & 1u)) >> 16);  // RNE
}
__device__ __forceinline__ float bf2f(unsigned short u) {
  return __uint_as_float(((unsigned int)u) << 16);
}

// pack hi16(a) | hi16(b)<<16 via v_perm_b32 (1 VALU op; trunc-to-bf16)
__device__ __forceinline__ unsigned int pack_trunc(float a, float b) {
  return __builtin_amdgcn_perm(__float_as_uint(b), __float_as_uint(a), 0x07060302u);
}

__device__ __forceinline__ float fmax3(float a, float b, float c) {
  return fmaxf(fmaxf(a, b), c);  // clang fuses to v_max3_f32
}

__device__ __forceinline__ void gload_lds16(const void* g, void* l) {
  __builtin_amdgcn_global_load_lds(
      (const __attribute__((address_space(1))) unsigned int*)g,
      (__attribute__((address_space(3))) unsigned int*)l, 16, 0, 0);
}

// ---------- prep: weight transposes (blocks 0..4095) + fp32->bf16 converts ----------
__global__ __launch_bounds__(256)
void k_prep(const float* __restrict__ x, unsigned short* __restrict__ xb,
            const float* __restrict__ out_w, unsigned short* __restrict__ OwB,
            const float* __restrict__ w0, const float* __restrict__ w1,
            const float* __restrict__ w2, const float* __restrict__ w3,
            unsigned short* __restrict__ o012, unsigned short* __restrict__ o3) {
  __shared__ float t[32][33];
  const int b = blockIdx.x;
  if (b < 4096) {
    const int m = b >> 10, rem = b & 1023;
    const float* in = m == 0 ? w0 : m == 1 ? w1 : m == 2 ? w2 : w3;
    unsigned short* out = m < 3 ? o012 + (size_t)m * 1048576 : o3;
    const int r0 = (rem >> 5) << 5, c0 = (rem & 31) << 5;
    const int tx = threadIdx.x & 31, ty = threadIdx.x >> 5;  // 32 x 8
#pragma unroll
    for (int rr = ty; rr < 32; rr += 8) t[rr][tx] = in[(size_t)(r0 + rr) * 1024 + c0 + tx];
    __syncthreads();
#pragma unroll
    for (int cc = ty; cc < 32; cc += 8)
      out[(size_t)(c0 + cc) * 1024 + r0 + tx] = f2bf(t[tx][cc]);
  } else {
    int i = (b - 4096) * 256 + threadIdx.x;
    const float* in;
    unsigned short* out;
    if (i < 1048576) { in = x; out = xb; }
    else { i -= 1048576; if (i >= 262144) return; in = out_w; out = OwB; }
    float4 v = ((const float4*)in)[i];
    u16x4 o;
    o.x = f2bf(v.x); o.y = f2bf(v.y); o.z = f2bf(v.z); o.w = f2bf(v.w);
    ((u16x4*)out)[i] = o;
  }
}

// ---------- bf16 GEMM 128x128, dbuf + 1 barrier/K-step (T3-min) ----------
// MODE 0: fp32 C.  MODE 1: bf16 C.  MODE 2: bf16 C for n0<VCOL0; cols >= VCOL0
// are written TRANSPOSED to VT[col-VCOL0][row] (fused V-transpose for attention).
template <int MODE>
__global__ __launch_bounds__(256)
void k_gemm_bt(const unsigned short* __restrict__ A, const unsigned short* __restrict__ BT,
               void* __restrict__ C, unsigned short* __restrict__ VT,
               int M, int N, int K) {
  const int VCOL0 = 2048;
  __shared__ __align__(16) unsigned short As[2][128 * 32];
  __shared__ __align__(16) unsigned short Bs[2][128 * 32];
  const int tid = threadIdx.x;
  const int wid = tid >> 6, lane = tid & 63;
  const int l16 = lane & 15, krow = lane >> 4;
  const int m0 = blockIdx.x * 128, n0 = blockIdx.y * 128;
  const int wr = wid >> 1, wc = wid & 1;  // 2x2 waves, 64x64 each

  f32x4 acc[4][4] = {};

  auto stageG = [&](int buf, int k0) {
#pragma unroll
    for (int j = 0; j < 2; j++) {
      int f = j * 256 + tid;
      gload_lds16(A  + (size_t)(m0 + (f >> 2)) * K + k0 + (f & 3) * 8,
                  (char*)As[buf] + (size_t)(j * 256 + wid * 64) * 16);
      gload_lds16(BT + (size_t)(n0 + (f >> 2)) * K + k0 + (f & 3) * 8,
                  (char*)Bs[buf] + (size_t)(j * 256 + wid * 64) * 16);
    }
  };
  auto comp = [&](int buf) {
    bf16x8 a[4], b[4];
#pragma unroll
    for (int i = 0; i < 4; i++) {
      a[i] = *(const bf16x8*)&As[buf][(wr * 64 + i * 16 + l16) * 32 + krow * 8];
      b[i] = *(const bf16x8*)&Bs[buf][(wc * 64 + i * 16 + l16) * 32 + krow * 8];
    }
#pragma unroll
    for (int mi = 0; mi < 4; mi++)
#pragma unroll
      for (int ni = 0; ni < 4; ni++)
        acc[mi][ni] = __builtin_amdgcn_mfma_f32_16x16x32_bf16(a[mi], b[ni], acc[mi][ni], 0, 0, 0);
  };

  stageG(0, 0);
  __syncthreads();
  for (int k0 = 0; k0 < K; k0 += 64) {
    if (k0 + 32 < K) stageG(1, k0 + 32);
    comp(0);
    __syncthreads();
    if (k0 + 64 < K) stageG(0, k0 + 64);
    comp(1);
    __syncthreads();
  }

  if (MODE == 2 && n0 >= VCOL0) {
    // V region: write transposed to VT[col - VCOL0][row] (rows consecutive per lane)
#pragma unroll
    for (int mi = 0; mi < 4; mi++)
#pragma unroll
      for (int ni = 0; ni < 4; ni++) {
        int col = n0 - VCOL0 + wc * 64 + ni * 16 + l16;
        int row = m0 + wr * 64 + mi * 16 + krow * 4;
        uint2 w;
        w.x = (unsigned)f2bf(acc[mi][ni][0]) | ((unsigned)f2bf(acc[mi][ni][1]) << 16);
        w.y = (unsigned)f2bf(acc[mi][ni][2]) | ((unsigned)f2bf(acc[mi][ni][3]) << 16);
        *(uint2*)&VT[(size_t)col * 4096 + row] = w;
      }
    return;
  }

#pragma unroll
  for (int mi = 0; mi < 4; mi++)
#pragma unroll
    for (int ni = 0; ni < 4; ni++)
#pragma unroll
      for (int r = 0; r < 4; r++) {
        int row = m0 + wr * 64 + mi * 16 + krow * 4 + r;
        int col = n0 + wc * 64 + ni * 16 + l16;
        float v = acc[mi][ni][r];
        if (MODE) ((unsigned short*)C)[(size_t)row * N + col] = f2bf(v);
        else      ((float*)C)[(size_t)row * N + col] = v;
      }
}

// ---------- bf16 GEMM 128x64, dbuf + 1 barrier/K-step ----------
template <int OUTBF>
__global__ __launch_bounds__(256)
void k_gemm_bt_n64(const unsigned short* __restrict__ A, const unsigned short* __restrict__ BT,
                   void* __restrict__ C, int M, int N, int K) {
  __shared__ __align__(16) unsigned short As[2][128 * 32];
  __shared__ __align__(16) unsigned short Bs[2][64 * 32];
  const int tid = threadIdx.x;
  const int wid = tid >> 6, lane = tid & 63;
  const int l16 = lane & 15, krow = lane >> 4;
  const int m0 = blockIdx.x * 128, n0 = blockIdx.y * 64;
  const int wr = wid >> 1, wc = wid & 1;  // 2x2 waves, 64x32 each

  f32x4 acc[4][2] = {};

  auto stageG = [&](int buf, int k0) {
#pragma unroll
    for (int j = 0; j < 2; j++) {
      int f = j * 256 + tid;
      gload_lds16(A + (size_t)(m0 + (f >> 2)) * K + k0 + (f & 3) * 8,
                  (char*)As[buf] + (size_t)(j * 256 + wid * 64) * 16);
    }
    gload_lds16(BT + (size_t)(n0 + (tid >> 2)) * K + k0 + (tid & 3) * 8,
                (char*)Bs[buf] + (size_t)(wid * 64) * 16);
  };
  auto comp = [&](int buf) {
    bf16x8 a[4], b[2];
#pragma unroll
    for (int i = 0; i < 4; i++)
      a[i] = *(const bf16x8*)&As[buf][(wr * 64 + i * 16 + l16) * 32 + krow * 8];
#pragma unroll
    for (int i = 0; i < 2; i++)
      b[i] = *(const bf16x8*)&Bs[buf][(wc * 32 + i * 16 + l16) * 32 + krow * 8];
#pragma unroll
    for (int mi = 0; mi < 4; mi++)
#pragma unroll
      for (int ni = 0; ni < 2; ni++)
        acc[mi][ni] = __builtin_amdgcn_mfma_f32_16x16x32_bf16(a[mi], b[ni], acc[mi][ni], 0, 0, 0);
  };

  stageG(0, 0);
  __syncthreads();
  for (int k0 = 0; k0 < K; k0 += 64) {
    if (k0 + 32 < K) stageG(1, k0 + 32);
    comp(0);
    __syncthreads();
    if (k0 + 64 < K) stageG(0, k0 + 64);
    comp(1);
    __syncthreads();
  }

#pragma unroll
  for (int mi = 0; mi < 4; mi++)
#pragma unroll
    for (int ni = 0; ni < 2; ni++)
#pragma unroll
      for (int r = 0; r < 4; r++) {
        int row = m0 + wr * 64 + mi * 16 + krow * 4 + r;
        int col = n0 + wc * 32 + ni * 16 + l16;
        float v = acc[mi][ni][r];
        if (OUTBF) ((unsigned short*)C)[(size_t)row * N + col] = f2bf(v);
        else       ((float*)C)[(size_t)row * N + col] = v;
      }
}

// ---------- flash attention (R10/R12 config: best measured) ----------
// 8 waves/WG (512 thr), 128 q-rows/WG, 16 q-rows/wave, grid 512 (16 heads x 32 qb).
// LDS 32 KB dbuf K+V -> 16 waves/CU. Swapped QK^T -> lane-local softmax
// (per-lane partial max, defer-max; per-lane partial l reduced in epilogue).
// PV: P^T B-frag = lane's own packed sacc under k-slot perm pi; V A-frag = two
// ds_read_b64 under the same pi.
__global__ __launch_bounds__(512)
void k_flash(const unsigned short* __restrict__ QKV, const unsigned short* __restrict__ Vt,
             unsigned short* __restrict__ ctx) {
  // shorts: dbuf 2 x (K 4096 | V 4096) = 32 KB
  __shared__ __align__(16) unsigned short LDS[16384];
  const int tid = threadIdx.x, wid = tid >> 6, lane = tid & 63;
  const int l16 = lane & 15, krow = lane >> 4;
  const int bid = blockIdx.x;
  const int swz = (bid & 7) * 64 + (bid >> 3);    // 512 % 8 == 0 -> bijective
  const int head = swz >> 5, qb = swz & 31;       // 2 heads per XCD (K/V/Q ~3MB < 4MB L2)
  const float SC = 0.125f * 1.44269504089f;       // scale into log2 domain

  // Q fragments (B-operand of swapped QK^T): lane holds q-row l16, d = ks*32+krow*8..+7
  bf16x8 qf[2];
#pragma unroll
  for (int ks = 0; ks < 2; ks++) {
    int row = qb * 128 + wid * 16 + l16;
    qf[ks] = *(const bf16x8*)&QKV[(size_t)row * 3072 + head * 64 + ks * 32 + krow * 8];
  }

  f32x4 oaccT[4] = {};      // O^T tiles [di]; col=q(l16), row=d(krow*4+r)
  float mrun = -INFINITY;   // uniform across the 4 krow-lanes of a q
  float lrun = 0.f;         // PER-LANE partial (reduced in epilogue)

  // one pass stages the whole 16 KB tile: 512 thr x (16B K + 16B V)
  auto stage = [&](int buf, int kt) {
    int row = tid >> 3, ch = tid & 7, sch = ch ^ (row & 7);  // pre-swizzled source
    gload_lds16(QKV + (size_t)(kt * 64 + row) * 3072 + 1024 + head * 64 + sch * 8,
                (char*)LDS + buf * 16384 + wid * 1024);          // + lane*16 by HW
    gload_lds16(Vt + (size_t)(head * 64 + row) * 4096 + kt * 64 + sch * 8,
                (char*)LDS + buf * 16384 + 8192 + wid * 1024);   // + lane*16 by HW
  };

  auto body = [&](int buf) {
    const unsigned short* Ks = LDS + buf * 8192;
    const char* VsB = (const char*)(LDS + buf * 8192 + 4096);

    // swapped QK^T: sacc[ni] = S^T tile [kv 16][q 16]; lane owns q=l16, kv=ni*16+krow*4+r
    f32x4 sacc[4] = {};
    __builtin_amdgcn_s_setprio(1);
#pragma unroll
    for (int ks = 0; ks < 2; ks++)
#pragma unroll
      for (int ni = 0; ni < 4; ni++) {
        int row = ni * 16 + l16;
        bf16x8 kf = *(const bf16x8*)&Ks[row * 64 + (((ks * 4 + krow) ^ (row & 7)) << 3)];
        sacc[ni] = __builtin_amdgcn_mfma_f32_16x16x32_bf16(kf, qf[ks], sacc[ni], 0, 0, 0);
      }
    __builtin_amdgcn_s_setprio(0);

    // per-lane partial max over this lane's 16 kv values (raw domain)
    float a = fmax3(sacc[0][0], sacc[0][1], sacc[0][2]);
    a = fmax3(a, sacc[0][3], sacc[1][0]);
    a = fmax3(a, sacc[1][1], sacc[1][2]);
    a = fmax3(a, sacc[1][3], sacc[2][0]);
    a = fmax3(a, sacc[2][1], sacc[2][2]);
    a = fmax3(a, sacc[2][3], sacc[3][0]);
    a = fmax3(a, sacc[3][1], sacc[3][2]);
    a = fmaxf(a, sacc[3][3]);

    // defer-max: cross-lane reduce + rescale only when some lane's partial
    // exceeds the running max by > 8 (log2 domain)
    if (__ballot(__builtin_fmaf(a, SC, -mrun) > 8.f)) {
      a = fmaxf(a, __shfl_xor(a, 16));
      a = fmaxf(a, __shfl_xor(a, 32));      // uniform per q now
      float mnew = fmaxf(mrun, a * SC);
      float al = __builtin_amdgcn_exp2f(mrun - mnew);
      lrun *= al;
      mrun = mnew;
#pragma unroll
      for (int di = 0; di < 4; di++)
#pragma unroll
        for (int r = 0; r < 4; r++) oaccT[di][r] *= al;
    }

    // P = exp2(s*SC - m); per-lane partial row-sum
#pragma unroll
    for (int ni = 0; ni < 4; ni++)
#pragma unroll
      for (int r = 0; r < 4; r++) {
        float p = __builtin_amdgcn_exp2f(__builtin_fmaf(sacc[ni][r], SC, -mrun));
        sacc[ni][r] = p;
        lrun += p;
      }

    // B-frags: P^T packed from this lane's OWN sacc under k-slot perm pi:
    //   pi(ks,krow,j) = (2ks + (j>>2))*16 + krow*4 + (j&3)
    union PB { unsigned int w[4]; bf16x8 v; };
    PB pb[2];
#pragma unroll
    for (int ks = 0; ks < 2; ks++) {
      pb[ks].w[0] = pack_trunc(sacc[2 * ks][0],     sacc[2 * ks][1]);
      pb[ks].w[1] = pack_trunc(sacc[2 * ks][2],     sacc[2 * ks][3]);
      pb[ks].w[2] = pack_trunc(sacc[2 * ks + 1][0], sacc[2 * ks + 1][1]);
      pb[ks].w[3] = pack_trunc(sacc[2 * ks + 1][2], sacc[2 * ks + 1][3]);
    }

    // O^T += V^T P^T: A-frag under same pi = two b64 reads from swizzled Vs
    __builtin_amdgcn_s_setprio(1);
#pragma unroll
    for (int ks = 0; ks < 2; ks++)
#pragma unroll
      for (int di = 0; di < 4; di++) {
        int row = di * 16 + l16;
        int base = row * 128 + ((krow & 1) << 3);
        union PB av;
        *(uint2*)&av.w[0] = *(const uint2*)(VsB + base + (((ks * 4 + (krow >> 1)) ^ (row & 7)) << 4));
        *(uint2*)&av.w[2] = *(const uint2*)(VsB + base + (((ks * 4 + 2 + (krow >> 1)) ^ (row & 7)) << 4));
        oaccT[di] = __builtin_amdgcn_mfma_f32_16x16x32_bf16(av.v, pb[ks].v, oaccT[di], 0, 0, 0);
      }
    __builtin_amdgcn_s_setprio(0);
  };

  stage(0, 0);
  __syncthreads();
  for (int kt = 0; kt < 64; kt += 2) {
    stage(1, kt + 1);
    body(0);
    __syncthreads();           // buf1 staged+drained; all reads of buf0 done
    if (kt + 2 < 64) stage(0, kt + 2);
    body(1);
    __syncthreads();
  }

  // epilogue: reduce per-lane l partials across the 4 krow-lanes of each q,
  // then per-lane normalize + 8B packed stores
  float lr = lrun;
  lr += __shfl_xor(lr, 16);
  lr += __shfl_xor(lr, 32);
  float li = 1.0f / lr;
  int row = qb * 128 + wid * 16 + l16;
#pragma unroll
  for (int di = 0; di < 4; di++) {
    uint2 w;
    w.x = (unsigned)f2bf(oaccT[di][0] * li) | ((unsigned)f2bf(oaccT[di][1] * li) << 16);
    w.y = (unsigned)f2bf(oaccT[di][2] * li) | ((unsigned)f2bf(oaccT[di][3] * li) << 16);
    *(uint2*)&ctx[(size_t)row * 1024 + head * 64 + di * 16 + krow * 4] = w;
  }
}

// ---------- LN(x + proj_bf16) -> bf16 only ----------
__global__ __launch_bounds__(256)
void k_ln_res(const float* __restrict__ base, const unsigned short* __restrict__ add,
              const float* __restrict__ g, const float* __restrict__ bb,
              unsigned short* __restrict__ outb) {
  const int r = blockIdx.x, tid = threadIdx.x;
  float4 v = ((const float4*)(base + (size_t)r * 1024))[tid];
  {
    u16x4 w = ((const u16x4*)(add + (size_t)r * 1024))[tid];
    v.x += bf2f(w.x); v.y += bf2f(w.y); v.z += bf2f(w.z); v.w += bf2f(w.w);
  }
  float s1 = v.x + v.y + v.z + v.w;
  float s2 = v.x * v.x + v.y * v.y + v.z * v.z + v.w * v.w;
#pragma unroll
  for (int off = 32; off >= 1; off >>= 1) { s1 += __shfl_xor(s1, off); s2 += __shfl_xor(s2, off); }
  __shared__ float red[8];
  if ((tid & 63) == 0) { red[tid >> 6] = s1; red[4 + (tid >> 6)] = s2; }
  __syncthreads();
  s1 = red[0] + red[1] + red[2] + red[3];
  s2 = red[4] + red[5] + red[6] + red[7];
  const float mu = s1 * (1.0f / 1024.0f);
  const float var = s2 * (1.0f / 1024.0f) - mu * mu;
  const float rs = rsqrtf(var + 1e-5f);
  float4 gv = ((const float4*)g)[tid];
  float4 bv = ((const float4*)bb)[tid];
  u16x4 o;
  o.x = f2bf((v.x - mu) * rs * gv.x + bv.x);
  o.y = f2bf((v.y - mu) * rs * gv.y + bv.y);
  o.z = f2bf((v.z - mu) * rs * gv.z + bv.z);
  o.w = f2bf((v.w - mu) * rs * gv.w + bv.w);
  ((u16x4*)(outb + (size_t)r * 1024))[tid] = o;
}

// ---------- relu(LN(lin_bf16 + out_b + mha_bf16)) -> fp32 out ----------
__global__ __launch_bounds__(256)
void k_ln2(const unsigned short* __restrict__ lin, const unsigned short* __restrict__ mha,
           const float* __restrict__ ob, const float* __restrict__ g,
           const float* __restrict__ bb, float* __restrict__ out) {
  const int r = blockIdx.x, tid = threadIdx.x;
  float4 v;
  {
    u16x4 a = ((const u16x4*)(lin + (size_t)r * 1024))[tid];
    u16x4 w = ((const u16x4*)(mha + (size_t)r * 1024))[tid];
    float4 o = ((const float4*)ob)[tid];
    v.x = bf2f(a.x) + bf2f(w.x) + o.x;
    v.y = bf2f(a.y) + bf2f(w.y) + o.y;
    v.z = bf2f(a.z) + bf2f(w.z) + o.z;
    v.w = bf2f(a.w) + bf2f(w.w) + o.w;
  }
  float s1 = v.x + v.y + v.z + v.w;
  float s2 = v.x * v.x + v.y * v.y + v.z * v.z + v.w * v.w;
#pragma unroll
  for (int off = 32; off >= 1; off >>= 1) { s1 += __shfl_xor(s1, off); s2 += __shfl_xor(s2, off); }
  __shared__ float red[8];
  if ((tid & 63) == 0) { red[tid >> 6] = s1; red[4 + (tid >> 6)] = s2; }
  __syncthreads();
  s1 = red[0] + red[1] + red[2] + red[3];
  s2 = red[4] + red[5] + red[6] + red[7];
  const float mu = s1 * (1.0f / 1024.0f);
  const float var = s2 * (1.0f / 1024.0f) - mu * mu;
  const float rs = rsqrtf(var + 1e-5f);
  float4 gv = ((const float4*)g)[tid];
  float4 bv = ((const float4*)bb)[tid];
  float4 y;
  y.x = fmaxf(0.f, (v.x - mu) * rs * gv.x + bv.x);
  y.y = fmaxf(0.f, (v.y - mu) * rs * gv.y + bv.y);
  y.z = fmaxf(0.f, (v.z - mu) * rs * gv.z + bv.z);
  y.w = fmaxf(0.f, (v.w - mu) * rs * gv.w + bv.w);
  ((float4*)(out + (size_t)r * 1024))[tid] = y;
}

// ---------- launch ----------
extern "C" void kernel_launch(void* const* d_in, const int* in_sizes, int n_in,
                              void* d_out, int out_size, void* d_ws, size_t ws_size,
                              hipStream_t stream) {
  (void)in_sizes; (void)n_in; (void)out_size; (void)ws_size;
  const float* x     = (const float*)d_in[0];
  const float* Wq    = (const float*)d_in[1];
  const float* Wk    = (const float*)d_in[2];
  const float* Wv    = (const float*)d_in[3];
  const float* Wo    = (const float*)d_in[4];
  const float* out_w = (const float*)d_in[5];
  const float* out_b = (const float*)d_in[6];
  const float* g1    = (const float*)d_in[7];
  const float* b1    = (const float*)d_in[8];
  const float* g2    = (const float*)d_in[9];
  const float* b2    = (const float*)d_in[10];
  float* out = (float*)d_out;

  // workspace layout (aliased; 60 MB total, liveness-checked)
  const size_t MB = 1ull << 20;
  char* ws = (char*)d_ws;
  unsigned short* xb    = (unsigned short*)(ws + 0);        // [4096][1024] bf16   (dead after GEMM1)
  unsigned short* WqkvT = (unsigned short*)(ws + 8 * MB);   // [3072][1024] bf16   (dead after GEMM1)
  unsigned short* OwB   = (unsigned short*)(ws + 16 * MB);  // out_w bf16 [1024][1024]
  unsigned short* QKV   = (unsigned short*)(ws + 18 * MB);  // [4096][3072] bf16 (Q,K used; V cols unwritten)
  unsigned short* Vt    = (unsigned short*)(ws + 42 * MB);  // [1024][4096] bf16   (dead after attn)
  unsigned short* ctx   = (unsigned short*)(ws + 50 * MB);  // [4096][1024] bf16   (dead after GEMM2)
  unsigned short* WoT   = (unsigned short*)(ws + 58 * MB);  // W_o^T bf16
  unsigned short* proj  = (unsigned short*)(ws + 0);        // [4096][1024] bf16 (over xb)
  unsigned short* mhaB  = (unsigned short*)(ws + 34 * MB);  // [4096][1024] bf16 (over QKV tail)
  unsigned short* lin   = (unsigned short*)(ws + 42 * MB);  // [4096][1024] bf16 (over Vt)

  k_prep<<<9216, 256, 0, stream>>>(x, xb, out_w, OwB, Wq, Wk, Wv, Wo, WqkvT, WoT);

  // GEMM1: QKV projection; V columns (n0>=2048) stream transposed into Vt
  k_gemm_bt<2><<<dim3(32, 24), 256, 0, stream>>>(xb, WqkvT, QKV, Vt, 4096, 3072, 1024);
  k_flash<<<512, 512, 0, stream>>>(QKV, Vt, ctx);
  k_gemm_bt_n64<1><<<dim3(32, 16), 256, 0, stream>>>(ctx, WoT, proj, 4096, 1024, 1024);
  k_ln_res<<<4096, 256, 0, stream>>>(x, proj, g1, b1, mhaB);
  k_gemm_bt_n64<1><<<dim3(32, 16), 256, 0, stream>>>(mhaB, OwB, lin, 4096, 1024, 1024);
  k_ln2<<<4096, 256, 0, stream>>>(lin, mhaB, out_b, g2, b2, out);
}

// Round 14
// 192.794 us; speedup vs baseline: 1.1601x; 1.0064x over previous
//
#include <hip/hip_runtime.h>
#include <cstdint>
#include <math.h>

// ---------- types ----------
typedef __attribute__((ext_vector_type(8))) short bf16x8;   // MFMA A/B operand (4 VGPRs)
typedef __attribute__((ext_vector_type(4))) float f32x4;    // MFMA C/D operand
typedef __attribute__((ext_vector_type(4))) unsigned short u16x4;

__device__ __forceinline__ unsigned short f2bf(float f) {
  union { float f; unsigned int u; } c; c.f = f;
  unsigned int u = c.u;
  return (unsigned short)((u + 0x7FFFu + ((u >> 16) & 1u)) >> 16);  // RNE
}
__device__ __forceinline__ float bf2f(unsigned short u) {
  return __uint_as_float(((unsigned int)u) << 16);
}

// pack hi16(a) | hi16(b)<<16 via v_perm_b32 (1 VALU op; trunc-to-bf16)
__device__ __forceinline__ unsigned int pack_trunc(float a, float b) {
  return __builtin_amdgcn_perm(__float_as_uint(b), __float_as_uint(a), 0x07060302u);
}

__device__ __forceinline__ float fmax3(float a, float b, float c) {
  return fmaxf(fmaxf(a, b), c);  // clang fuses to v_max3_f32
}

__device__ __forceinline__ void gload_lds16(const void* g, void* l) {
  __builtin_amdgcn_global_load_lds(
      (const __attribute__((address_space(1))) unsigned int*)g,
      (__attribute__((address_space(3))) unsigned int*)l, 16, 0, 0);
}

// ---------- prep: weight transposes (blocks 0..4095) + fp32->bf16 converts ----------
__global__ __launch_bounds__(256)
void k_prep(const float* __restrict__ x, unsigned short* __restrict__ xb,
            const float* __restrict__ out_w, unsigned short* __restrict__ OwB,
            const float* __restrict__ w0, const float* __restrict__ w1,
            const float* __restrict__ w2, const float* __restrict__ w3,
            unsigned short* __restrict__ o012, unsigned short* __restrict__ o3) {
  __shared__ float t[32][33];
  const int b = blockIdx.x;
  if (b < 4096) {
    const int m = b >> 10, rem = b & 1023;
    const float* in = m == 0 ? w0 : m == 1 ? w1 : m == 2 ? w2 : w3;
    unsigned short* out = m < 3 ? o012 + (size_t)m * 1048576 : o3;
    const int r0 = (rem >> 5) << 5, c0 = (rem & 31) << 5;
    const int tx = threadIdx.x & 31, ty = threadIdx.x >> 5;  // 32 x 8
#pragma unroll
    for (int rr = ty; rr < 32; rr += 8) t[rr][tx] = in[(size_t)(r0 + rr) * 1024 + c0 + tx];
    __syncthreads();
#pragma unroll
    for (int cc = ty; cc < 32; cc += 8)
      out[(size_t)(c0 + cc) * 1024 + r0 + tx] = f2bf(t[tx][cc]);
  } else {
    int i = (b - 4096) * 256 + threadIdx.x;
    const float* in;
    unsigned short* out;
    if (i < 1048576) { in = x; out = xb; }
    else { i -= 1048576; if (i >= 262144) return; in = out_w; out = OwB; }
    float4 v = ((const float4*)in)[i];
    u16x4 o;
    o.x = f2bf(v.x); o.y = f2bf(v.y); o.z = f2bf(v.z); o.w = f2bf(v.w);
    ((u16x4*)out)[i] = o;
  }
}

// ---------- bf16 GEMM 128x128, dbuf + 1 barrier/K-step (T3-min) ----------
// MODE 0: fp32 C.  MODE 1: bf16 C.  MODE 2: bf16 C for n0<VCOL0; cols >= VCOL0
// are written TRANSPOSED to VT[col-VCOL0][row] (fused V-transpose for attention).
template <int MODE>
__global__ __launch_bounds__(256)
void k_gemm_bt(const unsigned short* __restrict__ A, const unsigned short* __restrict__ BT,
               void* __restrict__ C, unsigned short* __restrict__ VT,
               int M, int N, int K) {
  const int VCOL0 = 2048;
  __shared__ __align__(16) unsigned short As[2][128 * 32];
  __shared__ __align__(16) unsigned short Bs[2][128 * 32];
  const int tid = threadIdx.x;
  const int wid = tid >> 6, lane = tid & 63;
  const int l16 = lane & 15, krow = lane >> 4;
  const int m0 = blockIdx.x * 128, n0 = blockIdx.y * 128;
  const int wr = wid >> 1, wc = wid & 1;  // 2x2 waves, 64x64 each

  f32x4 acc[4][4] = {};

  // hoisted LDS byte offsets for comp (buf0; buf1 via +8192 literal)
  unsigned aoff[4], boff[4];
#pragma unroll
  for (int i = 0; i < 4; i++) {
    aoff[i] = ((wr * 64 + i * 16 + l16) * 32 + krow * 8) * 2;
    boff[i] = ((wc * 64 + i * 16 + l16) * 32 + krow * 8) * 2;
  }

  auto stageG = [&](int buf, int k0) {
#pragma unroll
    for (int j = 0; j < 2; j++) {
      int f = j * 256 + tid;
      gload_lds16(A  + (size_t)(m0 + (f >> 2)) * K + k0 + (f & 3) * 8,
                  (char*)As[buf] + (size_t)(j * 256 + wid * 64) * 16);
      gload_lds16(BT + (size_t)(n0 + (f >> 2)) * K + k0 + (f & 3) * 8,
                  (char*)Bs[buf] + (size_t)(j * 256 + wid * 64) * 16);
    }
  };
  auto comp = [&](const int B) {  // B = buf byte offset (0 or 8192), literal
    bf16x8 a[4], b[4];
#pragma unroll
    for (int i = 0; i < 4; i++) {
      a[i] = *(const bf16x8*)((const char*)As[0] + B + aoff[i]);
      b[i] = *(const bf16x8*)((const char*)Bs[0] + B + boff[i]);
    }
#pragma unroll
    for (int mi = 0; mi < 4; mi++)
#pragma unroll
      for (int ni = 0; ni < 4; ni++)
        acc[mi][ni] = __builtin_amdgcn_mfma_f32_16x16x32_bf16(a[mi], b[ni], acc[mi][ni], 0, 0, 0);
  };

  stageG(0, 0);
  __syncthreads();
  for (int k0 = 0; k0 < K; k0 += 64) {
    if (k0 + 32 < K) stageG(1, k0 + 32);
    comp(0);
    __syncthreads();
    if (k0 + 64 < K) stageG(0, k0 + 64);
    comp(8192);
    __syncthreads();
  }

  if (MODE == 2 && n0 >= VCOL0) {
    // V region: write transposed to VT[col - VCOL0][row] (rows consecutive per lane)
#pragma unroll
    for (int mi = 0; mi < 4; mi++)
#pragma unroll
      for (int ni = 0; ni < 4; ni++) {
        int col = n0 - VCOL0 + wc * 64 + ni * 16 + l16;
        int row = m0 + wr * 64 + mi * 16 + krow * 4;
        uint2 w;
        w.x = (unsigned)f2bf(acc[mi][ni][0]) | ((unsigned)f2bf(acc[mi][ni][1]) << 16);
        w.y = (unsigned)f2bf(acc[mi][ni][2]) | ((unsigned)f2bf(acc[mi][ni][3]) << 16);
        *(uint2*)&VT[(size_t)col * 4096 + row] = w;
      }
    return;
  }

#pragma unroll
  for (int mi = 0; mi < 4; mi++)
#pragma unroll
    for (int ni = 0; ni < 4; ni++)
#pragma unroll
      for (int r = 0; r < 4; r++) {
        int row = m0 + wr * 64 + mi * 16 + krow * 4 + r;
        int col = n0 + wc * 64 + ni * 16 + l16;
        float v = acc[mi][ni][r];
        if (MODE) ((unsigned short*)C)[(size_t)row * N + col] = f2bf(v);
        else      ((float*)C)[(size_t)row * N + col] = v;
      }
}

// ---------- bf16 GEMM 128x64, dbuf + 1 barrier/K-step ----------
template <int OUTBF>
__global__ __launch_bounds__(256)
void k_gemm_bt_n64(const unsigned short* __restrict__ A, const unsigned short* __restrict__ BT,
                   void* __restrict__ C, int M, int N, int K) {
  __shared__ __align__(16) unsigned short As[2][128 * 32];
  __shared__ __align__(16) unsigned short Bs[2][64 * 32];
  const int tid = threadIdx.x;
  const int wid = tid >> 6, lane = tid & 63;
  const int l16 = lane & 15, krow = lane >> 4;
  const int m0 = blockIdx.x * 128, n0 = blockIdx.y * 64;
  const int wr = wid >> 1, wc = wid & 1;  // 2x2 waves, 64x32 each

  f32x4 acc[4][2] = {};

  unsigned aoff[4], boff[2];
#pragma unroll
  for (int i = 0; i < 4; i++)
    aoff[i] = ((wr * 64 + i * 16 + l16) * 32 + krow * 8) * 2;
#pragma unroll
  for (int i = 0; i < 2; i++)
    boff[i] = ((wc * 32 + i * 16 + l16) * 32 + krow * 8) * 2;

  auto stageG = [&](int buf, int k0) {
#pragma unroll
    for (int j = 0; j < 2; j++) {
      int f = j * 256 + tid;
      gload_lds16(A + (size_t)(m0 + (f >> 2)) * K + k0 + (f & 3) * 8,
                  (char*)As[buf] + (size_t)(j * 256 + wid * 64) * 16);
    }
    gload_lds16(BT + (size_t)(n0 + (tid >> 2)) * K + k0 + (tid & 3) * 8,
                (char*)Bs[buf] + (size_t)(wid * 64) * 16);
  };
  auto comp = [&](const int AB, const int BB) {  // byte offsets: A buf (0/8192), B buf (0/4096)
    bf16x8 a[4], b[2];
#pragma unroll
    for (int i = 0; i < 4; i++)
      a[i] = *(const bf16x8*)((const char*)As[0] + AB + aoff[i]);
#pragma unroll
    for (int i = 0; i < 2; i++)
      b[i] = *(const bf16x8*)((const char*)Bs[0] + BB + boff[i]);
#pragma unroll
    for (int mi = 0; mi < 4; mi++)
#pragma unroll
      for (int ni = 0; ni < 2; ni++)
        acc[mi][ni] = __builtin_amdgcn_mfma_f32_16x16x32_bf16(a[mi], b[ni], acc[mi][ni], 0, 0, 0);
  };

  stageG(0, 0);
  __syncthreads();
  for (int k0 = 0; k0 < K; k0 += 64) {
    if (k0 + 32 < K) stageG(1, k0 + 32);
    comp(0, 0);
    __syncthreads();
    if (k0 + 64 < K) stageG(0, k0 + 64);
    comp(8192, 4096);
    __syncthreads();
  }

#pragma unroll
  for (int mi = 0; mi < 4; mi++)
#pragma unroll
    for (int ni = 0; ni < 2; ni++)
#pragma unroll
      for (int r = 0; r < 4; r++) {
        int row = m0 + wr * 64 + mi * 16 + krow * 4 + r;
        int col = n0 + wc * 32 + ni * 16 + l16;
        float v = acc[mi][ni][r];
        if (OUTBF) ((unsigned short*)C)[(size_t)row * N + col] = f2bf(v);
        else       ((float*)C)[(size_t)row * N + col] = v;
      }
}

// ---------- flash attention (R10/R12 structure + hoisted addresses) ----------
// 8 waves/WG (512 thr), 128 q-rows/WG, 16 q-rows/wave, grid 512 (16 heads x 32 qb).
// LDS 32 KB dbuf K+V -> 16 waves/CU. Swapped QK^T -> lane-local softmax
// (per-lane partial max, defer-max; per-lane partial l reduced in epilogue).
// PV: P^T B-frag = lane's own packed sacc under k-slot perm pi; V A-frag = two
// ds_read_b64 under the same pi. ALL LDS read offsets hoisted to registers;
// buffer select via literal imm offset (0/16384); staging sources are cursors.
__global__ __launch_bounds__(512)
void k_flash(const unsigned short* __restrict__ QKV, const unsigned short* __restrict__ Vt,
             unsigned short* __restrict__ ctx) {
  // shorts: dbuf 2 x (K 4096 | V 4096) = 32 KB
  __shared__ __align__(16) unsigned short LDS[16384];
  const int tid = threadIdx.x, wid = tid >> 6, lane = tid & 63;
  const int l16 = lane & 15, krow = lane >> 4;
  const int bid = blockIdx.x;
  const int swz = (bid & 7) * 64 + (bid >> 3);    // 512 % 8 == 0 -> bijective
  const int head = swz >> 5, qb = swz & 31;       // 2 heads per XCD (K/V/Q ~3MB < 4MB L2)
  const float SC = 0.125f * 1.44269504089f;       // scale into log2 domain

  // Q fragments (B-operand of swapped QK^T): lane holds q-row l16, d = ks*32+krow*8..+7
  bf16x8 qf[2];
#pragma unroll
  for (int ks = 0; ks < 2; ks++) {
    int row = qb * 128 + wid * 16 + l16;
    qf[ks] = *(const bf16x8*)&QKV[(size_t)row * 3072 + head * 64 + ks * 32 + krow * 8];
  }

  // hoisted LDS byte offsets (buf0; buf1 selected by +16384 literal imm)
  unsigned koff[2][4], va0[2][4], va1[2][4];
#pragma unroll
  for (int ks = 0; ks < 2; ks++)
#pragma unroll
    for (int ni = 0; ni < 4; ni++) {
      int row = ni * 16 + l16;
      koff[ks][ni] = row * 128 + (((ks * 4 + krow) ^ (row & 7)) << 4);
      va0[ks][ni] = 8192 + row * 128 + ((krow & 1) << 3)
                  + (((ks * 4 + (krow >> 1)) ^ (row & 7)) << 4);
      va1[ks][ni] = 8192 + row * 128 + ((krow & 1) << 3)
                  + (((ks * 4 + 2 + (krow >> 1)) ^ (row & 7)) << 4);
    }

  // staging source cursors (advance once per staged tile) + fixed LDS dests
  const unsigned short* kSrc;
  const unsigned short* vSrc;
  {
    int row = tid >> 3, sch = (tid & 7) ^ (row & 7);  // pre-swizzled source
    kSrc = QKV + (size_t)row * 3072 + 1024 + head * 64 + sch * 8;
    vSrc = Vt + (size_t)(head * 64 + row) * 4096 + sch * 8;
  }
  char* dK = (char*)LDS + wid * 1024;           // + lane*16 by HW
  char* dV = (char*)LDS + 8192 + wid * 1024;

  f32x4 oaccT[4] = {};      // O^T tiles [di]; col=q(l16), row=d(krow*4+r)
  float mrun = -INFINITY;   // uniform across the 4 krow-lanes of a q
  float lrun = 0.f;         // PER-LANE partial (reduced in epilogue)

  auto stage = [&](const int B) {
    gload_lds16(kSrc, dK + B);
    gload_lds16(vSrc, dV + B);
    kSrc += 64 * 3072;
    vSrc += 64;
  };

  auto body = [&](const int B) {  // B = buf byte offset (0 or 16384), literal
    const char* L = (const char*)LDS;

    // swapped QK^T: sacc[ni] = S^T tile [kv 16][q 16]; lane owns q=l16, kv=ni*16+krow*4+r
    f32x4 sacc[4] = {};
    __builtin_amdgcn_s_setprio(1);
#pragma unroll
    for (int ks = 0; ks < 2; ks++)
#pragma unroll
      for (int ni = 0; ni < 4; ni++) {
        bf16x8 kf = *(const bf16x8*)(L + B + koff[ks][ni]);
        sacc[ni] = __builtin_amdgcn_mfma_f32_16x16x32_bf16(kf, qf[ks], sacc[ni], 0, 0, 0);
      }
    __builtin_amdgcn_s_setprio(0);

    // per-lane partial max over this lane's 16 kv values (raw domain)
    float a = fmax3(sacc[0][0], sacc[0][1], sacc[0][2]);
    a = fmax3(a, sacc[0][3], sacc[1][0]);
    a = fmax3(a, sacc[1][1], sacc[1][2]);
    a = fmax3(a, sacc[1][3], sacc[2][0]);
    a = fmax3(a, sacc[2][1], sacc[2][2]);
    a = fmax3(a, sacc[2][3], sacc[3][0]);
    a = fmax3(a, sacc[3][1], sacc[3][2]);
    a = fmaxf(a, sacc[3][3]);

    // defer-max: cross-lane reduce + rescale only when some lane's partial
    // exceeds the running max by > 8 (log2 domain)
    if (__ballot(__builtin_fmaf(a, SC, -mrun) > 8.f)) {
      a = fmaxf(a, __shfl_xor(a, 16));
      a = fmaxf(a, __shfl_xor(a, 32));      // uniform per q now
      float mnew = fmaxf(mrun, a * SC);
      float al = __builtin_amdgcn_exp2f(mrun - mnew);
      lrun *= al;
      mrun = mnew;
#pragma unroll
      for (int di = 0; di < 4; di++)
#pragma unroll
        for (int r = 0; r < 4; r++) oaccT[di][r] *= al;
    }

    // P = exp2(s*SC - m); per-lane partial row-sum (tree-reduced add chain)
    float ps[4];
#pragma unroll
    for (int ni = 0; ni < 4; ni++) {
      float p0 = __builtin_amdgcn_exp2f(__builtin_fmaf(sacc[ni][0], SC, -mrun));
      float p1 = __builtin_amdgcn_exp2f(__builtin_fmaf(sacc[ni][1], SC, -mrun));
      float p2 = __builtin_amdgcn_exp2f(__builtin_fmaf(sacc[ni][2], SC, -mrun));
      float p3 = __builtin_amdgcn_exp2f(__builtin_fmaf(sacc[ni][3], SC, -mrun));
      sacc[ni][0] = p0; sacc[ni][1] = p1; sacc[ni][2] = p2; sacc[ni][3] = p3;
      ps[ni] = (p0 + p1) + (p2 + p3);
    }
    lrun += (ps[0] + ps[1]) + (ps[2] + ps[3]);

    // B-frags: P^T packed from this lane's OWN sacc under k-slot perm pi:
    //   pi(ks,krow,j) = (2ks + (j>>2))*16 + krow*4 + (j&3)
    union PB { unsigned int w[4]; bf16x8 v; };
    PB pb[2];
#pragma unroll
    for (int ks = 0; ks < 2; ks++) {
      pb[ks].w[0] = pack_trunc(sacc[2 * ks][0],     sacc[2 * ks][1]);
      pb[ks].w[1] = pack_trunc(sacc[2 * ks][2],     sacc[2 * ks][3]);
      pb[ks].w[2] = pack_trunc(sacc[2 * ks + 1][0], sacc[2 * ks + 1][1]);
      pb[ks].w[3] = pack_trunc(sacc[2 * ks + 1][2], sacc[2 * ks + 1][3]);
    }

    // O^T += V^T P^T: A-frag under same pi = two b64 reads (hoisted offsets)
    __builtin_amdgcn_s_setprio(1);
#pragma unroll
    for (int ks = 0; ks < 2; ks++)
#pragma unroll
      for (int di = 0; di < 4; di++) {
        union PB av;
        *(uint2*)&av.w[0] = *(const uint2*)(L + B + va0[ks][di]);
        *(uint2*)&av.w[2] = *(const uint2*)(L + B + va1[ks][di]);
        oaccT[di] = __builtin_amdgcn_mfma_f32_16x16x32_bf16(av.v, pb[ks].v, oaccT[di], 0, 0, 0);
      }
    __builtin_amdgcn_s_setprio(0);
  };

  stage(0);
  __syncthreads();
  for (int kt = 0; kt < 64; kt += 2) {
    stage(16384);
    body(0);
    __syncthreads();           // buf1 staged+drained; all reads of buf0 done
    if (kt + 2 < 64) stage(0);
    body(16384);
    __syncthreads();
  }

  // epilogue: reduce per-lane l partials across the 4 krow-lanes of each q,
  // then per-lane normalize + 8B packed stores
  float lr = lrun;
  lr += __shfl_xor(lr, 16);
  lr += __shfl_xor(lr, 32);
  float li = 1.0f / lr;
  int row = qb * 128 + wid * 16 + l16;
#pragma unroll
  for (int di = 0; di < 4; di++) {
    uint2 w;
    w.x = (unsigned)f2bf(oaccT[di][0] * li) | ((unsigned)f2bf(oaccT[di][1] * li) << 16);
    w.y = (unsigned)f2bf(oaccT[di][2] * li) | ((unsigned)f2bf(oaccT[di][3] * li) << 16);
    *(uint2*)&ctx[(size_t)row * 1024 + head * 64 + di * 16 + krow * 4] = w;
  }
}

// ---------- LN(x + proj_bf16) -> bf16 only ----------
__global__ __launch_bounds__(256)
void k_ln_res(const float* __restrict__ base, const unsigned short* __restrict__ add,
              const float* __restrict__ g, const float* __restrict__ bb,
              unsigned short* __restrict__ outb) {
  const int r = blockIdx.x, tid = threadIdx.x;
  float4 v = ((const float4*)(base + (size_t)r * 1024))[tid];
  {
    u16x4 w = ((const u16x4*)(add + (size_t)r * 1024))[tid];
    v.x += bf2f(w.x); v.y += bf2f(w.y); v.z += bf2f(w.z); v.w += bf2f(w.w);
  }
  float s1 = v.x + v.y + v.z + v.w;
  float s2 = v.x * v.x + v.y * v.y + v.z * v.z + v.w * v.w;
#pragma unroll
  for (int off = 32; off >= 1; off >>= 1) { s1 += __shfl_xor(s1, off); s2 += __shfl_xor(s2, off); }
  __shared__ float red[8];
  if ((tid & 63) == 0) { red[tid >> 6] = s1; red[4 + (tid >> 6)] = s2; }
  __syncthreads();
  s1 = red[0] + red[1] + red[2] + red[3];
  s2 = red[4] + red[5] + red[6] + red[7];
  const float mu = s1 * (1.0f / 1024.0f);
  const float var = s2 * (1.0f / 1024.0f) - mu * mu;
  const float rs = rsqrtf(var + 1e-5f);
  float4 gv = ((const float4*)g)[tid];
  float4 bv = ((const float4*)bb)[tid];
  u16x4 o;
  o.x = f2bf((v.x - mu) * rs * gv.x + bv.x);
  o.y = f2bf((v.y - mu) * rs * gv.y + bv.y);
  o.z = f2bf((v.z - mu) * rs * gv.z + bv.z);
  o.w = f2bf((v.w - mu) * rs * gv.w + bv.w);
  ((u16x4*)(outb + (size_t)r * 1024))[tid] = o;
}

// ---------- relu(LN(lin_bf16 + out_b + mha_bf16)) -> fp32 out ----------
__global__ __launch_bounds__(256)
void k_ln2(const unsigned short* __restrict__ lin, const unsigned short* __restrict__ mha,
           const float* __restrict__ ob, const float* __restrict__ g,
           const float* __restrict__ bb, float* __restrict__ out) {
  const int r = blockIdx.x, tid = threadIdx.x;
  float4 v;
  {
    u16x4 a = ((const u16x4*)(lin + (size_t)r * 1024))[tid];
    u16x4 w = ((const u16x4*)(mha + (size_t)r * 1024))[tid];
    float4 o = ((const float4*)ob)[tid];
    v.x = bf2f(a.x) + bf2f(w.x) + o.x;
    v.y = bf2f(a.y) + bf2f(w.y) + o.y;
    v.z = bf2f(a.z) + bf2f(w.z) + o.z;
    v.w = bf2f(a.w) + bf2f(w.w) + o.w;
  }
  float s1 = v.x + v.y + v.z + v.w;
  float s2 = v.x * v.x + v.y * v.y + v.z * v.z + v.w * v.w;
#pragma unroll
  for (int off = 32; off >= 1; off >>= 1) { s1 += __shfl_xor(s1, off); s2 += __shfl_xor(s2, off); }
  __shared__ float red[8];
  if ((tid & 63) == 0) { red[tid >> 6] = s1; red[4 + (tid >> 6)] = s2; }
  __syncthreads();
  s1 = red[0] + red[1] + red[2] + red[3];
  s2 = red[4] + red[5] + red[6] + red[7];
  const float mu = s1 * (1.0f / 1024.0f);
  const float var = s2 * (1.0f / 1024.0f) - mu * mu;
  const float rs = rsqrtf(var + 1e-5f);
  float4 gv = ((const float4*)g)[tid];
  float4 bv = ((const float4*)bb)[tid];
  float4 y;
  y.x = fmaxf(0.f, (v.x - mu) * rs * gv.x + bv.x);
  y.y = fmaxf(0.f, (v.y - mu) * rs * gv.y + bv.y);
  y.z = fmaxf(0.f, (v.z - mu) * rs * gv.z + bv.z);
  y.w = fmaxf(0.f, (v.w - mu) * rs * gv.w + bv.w);
  ((float4*)(out + (size_t)r * 1024))[tid] = y;
}

// ---------- launch ----------
extern "C" void kernel_launch(void* const* d_in, const int* in_sizes, int n_in,
                              void* d_out, int out_size, void* d_ws, size_t ws_size,
                              hipStream_t stream) {
  (void)in_sizes; (void)n_in; (void)out_size; (void)ws_size;
  const float* x     = (const float*)d_in[0];
  const float* Wq    = (const float*)d_in[1];
  const float* Wk    = (const float*)d_in[2];
  const float* Wv    = (const float*)d_in[3];
  const float* Wo    = (const float*)d_in[4];
  const float* out_w = (const float*)d_in[5];
  const float* out_b = (const float*)d_in[6];
  const float* g1    = (const float*)d_in[7];
  const float* b1    = (const float*)d_in[8];
  const float* g2    = (const float*)d_in[9];
  const float* b2    = (const float*)d_in[10];
  float* out = (float*)d_out;

  // workspace layout (aliased; 60 MB total, liveness-checked)
  const size_t MB = 1ull << 20;
  char* ws = (char*)d_ws;
  unsigned short* xb    = (unsigned short*)(ws + 0);        // [4096][1024] bf16   (dead after GEMM1)
  unsigned short* WqkvT = (unsigned short*)(ws + 8 * MB);   // [3072][1024] bf16   (dead after GEMM1)
  unsigned short* OwB   = (unsigned short*)(ws + 16 * MB);  // out_w bf16 [1024][1024]
  unsigned short* QKV   = (unsigned short*)(ws + 18 * MB);  // [4096][3072] bf16 (Q,K used; V cols unwritten)
  unsigned short* Vt    = (unsigned short*)(ws + 42 * MB);  // [1024][4096] bf16   (dead after attn)
  unsigned short* ctx   = (unsigned short*)(ws + 50 * MB);  // [4096][1024] bf16   (dead after GEMM2)
  unsigned short* WoT   = (unsigned short*)(ws + 58 * MB);  // W_o^T bf16
  unsigned short* proj  = (unsigned short*)(ws + 0);        // [4096][1024] bf16 (over xb)
  unsigned short* mhaB  = (unsigned short*)(ws + 34 * MB);  // [4096][1024] bf16 (over QKV tail)
  unsigned short* lin   = (unsigned short*)(ws + 42 * MB);  // [4096][1024] bf16 (over Vt)

  k_prep<<<9216, 256, 0, stream>>>(x, xb, out_w, OwB, Wq, Wk, Wv, Wo, WqkvT, WoT);

  // GEMM1: QKV projection; V columns (n0>=2048) stream transposed into Vt
  k_gemm_bt<2><<<dim3(32, 24), 256, 0, stream>>>(xb, WqkvT, QKV, Vt, 4096, 3072, 1024);
  k_flash<<<512, 512, 0, stream>>>(QKV, Vt, ctx);
  k_gemm_bt_n64<1><<<dim3(32, 16), 256, 0, stream>>>(ctx, WoT, proj, 4096, 1024, 1024);
  k_ln_res<<<4096, 256, 0, stream>>>(x, proj, g1, b1, mhaB);
  k_gemm_bt_n64<1><<<dim3(32, 16), 256, 0, stream>>>(mhaB, OwB, lin, 4096, 1024, 1024);
  k_ln2<<<4096, 256, 0, stream>>>(lin, mhaB, out_b, g2, b2, out);
}

// Round 15
// 187.387 us; speedup vs baseline: 1.1935x; 1.0289x over previous
//
#include <hip/hip_runtime.h>
#include <cstdint>
#include <math.h>

// ---------- types ----------
typedef __attribute__((ext_vector_type(8))) short bf16x8;   // MFMA A/B operand (4 VGPRs)
typedef __attribute__((ext_vector_type(4))) float f32x4;    // MFMA C/D operand
typedef __attribute__((ext_vector_type(4))) unsigned short u16x4;

__device__ __forceinline__ unsigned short f2bf(float f) {
  union { float f; unsigned int u; } c; c.f = f;
  unsigned int u = c.u;
  return (unsigned short)((u + 0x7FFFu + ((u >> 16) & 1u)) >> 16);  // RNE
}
__device__ __forceinline__ float bf2f(unsigned short u) {
  return __uint_as_float(((unsigned int)u) << 16);
}

// pack hi16(a) | hi16(b)<<16 via v_perm_b32 (1 VALU op; trunc-to-bf16)
__device__ __forceinline__ unsigned int pack_trunc(float a, float b) {
  return __builtin_amdgcn_perm(__float_as_uint(b), __float_as_uint(a), 0x07060302u);
}

__device__ __forceinline__ float fmax3(float a, float b, float c) {
  return fmaxf(fmaxf(a, b), c);  // clang fuses to v_max3_f32
}

__device__ __forceinline__ void gload_lds16(const void* g, void* l) {
  __builtin_amdgcn_global_load_lds(
      (const __attribute__((address_space(1))) unsigned int*)g,
      (__attribute__((address_space(3))) unsigned int*)l, 16, 0, 0);
}

// ---------- prep: weight transposes (blocks 0..4095) + fp32->bf16 converts ----------
__global__ __launch_bounds__(256)
void k_prep(const float* __restrict__ x, unsigned short* __restrict__ xb,
            const float* __restrict__ out_w, unsigned short* __restrict__ OwB,
            const float* __restrict__ w0, const float* __restrict__ w1,
            const float* __restrict__ w2, const float* __restrict__ w3,
            unsigned short* __restrict__ o012, unsigned short* __restrict__ o3) {
  __shared__ float t[32][33];
  const int b = blockIdx.x;
  if (b < 4096) {
    const int m = b >> 10, rem = b & 1023;
    const float* in = m == 0 ? w0 : m == 1 ? w1 : m == 2 ? w2 : w3;
    unsigned short* out = m < 3 ? o012 + (size_t)m * 1048576 : o3;
    const int r0 = (rem >> 5) << 5, c0 = (rem & 31) << 5;
    const int tx = threadIdx.x & 31, ty = threadIdx.x >> 5;  // 32 x 8
#pragma unroll
    for (int rr = ty; rr < 32; rr += 8) t[rr][tx] = in[(size_t)(r0 + rr) * 1024 + c0 + tx];
    __syncthreads();
#pragma unroll
    for (int cc = ty; cc < 32; cc += 8)
      out[(size_t)(c0 + cc) * 1024 + r0 + tx] = f2bf(t[tx][cc]);
  } else {
    int i = (b - 4096) * 256 + threadIdx.x;
    const float* in;
    unsigned short* out;
    if (i < 1048576) { in = x; out = xb; }
    else { i -= 1048576; if (i >= 262144) return; in = out_w; out = OwB; }
    float4 v = ((const float4*)in)[i];
    u16x4 o;
    o.x = f2bf(v.x); o.y = f2bf(v.y); o.z = f2bf(v.z); o.w = f2bf(v.w);
    ((u16x4*)out)[i] = o;
  }
}

// ---------- bf16 GEMM 128x128, dbuf + 1 barrier/K-step (T3-min) ----------
// MODE 0: fp32 C.  MODE 1: bf16 C.  MODE 2: bf16 C for n0<VCOL0; cols >= VCOL0
// are written TRANSPOSED to VT[col-VCOL0][row] (fused V-transpose for attention).
template <int MODE>
__global__ __launch_bounds__(256)
void k_gemm_bt(const unsigned short* __restrict__ A, const unsigned short* __restrict__ BT,
               void* __restrict__ C, unsigned short* __restrict__ VT,
               int M, int N, int K) {
  const int VCOL0 = 2048;
  __shared__ __align__(16) unsigned short As[2][128 * 32];
  __shared__ __align__(16) unsigned short Bs[2][128 * 32];
  const int tid = threadIdx.x;
  const int wid = tid >> 6, lane = tid & 63;
  const int l16 = lane & 15, krow = lane >> 4;
  const int m0 = blockIdx.x * 128, n0 = blockIdx.y * 128;
  const int wr = wid >> 1, wc = wid & 1;  // 2x2 waves, 64x64 each

  f32x4 acc[4][4] = {};

  auto stageG = [&](int buf, int k0) {
#pragma unroll
    for (int j = 0; j < 2; j++) {
      int f = j * 256 + tid;
      gload_lds16(A  + (size_t)(m0 + (f >> 2)) * K + k0 + (f & 3) * 8,
                  (char*)As[buf] + (size_t)(j * 256 + wid * 64) * 16);
      gload_lds16(BT + (size_t)(n0 + (f >> 2)) * K + k0 + (f & 3) * 8,
                  (char*)Bs[buf] + (size_t)(j * 256 + wid * 64) * 16);
    }
  };
  auto comp = [&](int buf) {
    bf16x8 a[4], b[4];
#pragma unroll
    for (int i = 0; i < 4; i++) {
      a[i] = *(const bf16x8*)&As[buf][(wr * 64 + i * 16 + l16) * 32 + krow * 8];
      b[i] = *(const bf16x8*)&Bs[buf][(wc * 64 + i * 16 + l16) * 32 + krow * 8];
    }
#pragma unroll
    for (int mi = 0; mi < 4; mi++)
#pragma unroll
      for (int ni = 0; ni < 4; ni++)
        acc[mi][ni] = __builtin_amdgcn_mfma_f32_16x16x32_bf16(a[mi], b[ni], acc[mi][ni], 0, 0, 0);
  };

  stageG(0, 0);
  __syncthreads();
  for (int k0 = 0; k0 < K; k0 += 64) {
    if (k0 + 32 < K) stageG(1, k0 + 32);
    comp(0);
    __syncthreads();
    if (k0 + 64 < K) stageG(0, k0 + 64);
    comp(1);
    __syncthreads();
  }

  if (MODE == 2 && n0 >= VCOL0) {
    // V region: write transposed to VT[col - VCOL0][row] (rows consecutive per lane)
#pragma unroll
    for (int mi = 0; mi < 4; mi++)
#pragma unroll
      for (int ni = 0; ni < 4; ni++) {
        int col = n0 - VCOL0 + wc * 64 + ni * 16 + l16;
        int row = m0 + wr * 64 + mi * 16 + krow * 4;
        uint2 w;
        w.x = (unsigned)f2bf(acc[mi][ni][0]) | ((unsigned)f2bf(acc[mi][ni][1]) << 16);
        w.y = (unsigned)f2bf(acc[mi][ni][2]) | ((unsigned)f2bf(acc[mi][ni][3]) << 16);
        *(uint2*)&VT[(size_t)col * 4096 + row] = w;
      }
    return;
  }

#pragma unroll
  for (int mi = 0; mi < 4; mi++)
#pragma unroll
    for (int ni = 0; ni < 4; ni++)
#pragma unroll
      for (int r = 0; r < 4; r++) {
        int row = m0 + wr * 64 + mi * 16 + krow * 4 + r;
        int col = n0 + wc * 64 + ni * 16 + l16;
        float v = acc[mi][ni][r];
        if (MODE) ((unsigned short*)C)[(size_t)row * N + col] = f2bf(v);
        else      ((float*)C)[(size_t)row * N + col] = v;
      }
}

// ---------- bf16 GEMM 128x64, dbuf + 1 barrier/K-step ----------
template <int OUTBF>
__global__ __launch_bounds__(256)
void k_gemm_bt_n64(const unsigned short* __restrict__ A, const unsigned short* __restrict__ BT,
                   void* __restrict__ C, int M, int N, int K) {
  __shared__ __align__(16) unsigned short As[2][128 * 32];
  __shared__ __align__(16) unsigned short Bs[2][64 * 32];
  const int tid = threadIdx.x;
  const int wid = tid >> 6, lane = tid & 63;
  const int l16 = lane & 15, krow = lane >> 4;
  const int m0 = blockIdx.x * 128, n0 = blockIdx.y * 64;
  const int wr = wid >> 1, wc = wid & 1;  // 2x2 waves, 64x32 each

  f32x4 acc[4][2] = {};

  auto stageG = [&](int buf, int k0) {
#pragma unroll
    for (int j = 0; j < 2; j++) {
      int f = j * 256 + tid;
      gload_lds16(A + (size_t)(m0 + (f >> 2)) * K + k0 + (f & 3) * 8,
                  (char*)As[buf] + (size_t)(j * 256 + wid * 64) * 16);
    }
    gload_lds16(BT + (size_t)(n0 + (tid >> 2)) * K + k0 + (tid & 3) * 8,
                (char*)Bs[buf] + (size_t)(wid * 64) * 16);
  };
  auto comp = [&](int buf) {
    bf16x8 a[4], b[2];
#pragma unroll
    for (int i = 0; i < 4; i++)
      a[i] = *(const bf16x8*)&As[buf][(wr * 64 + i * 16 + l16) * 32 + krow * 8];
#pragma unroll
    for (int i = 0; i < 2; i++)
      b[i] = *(const bf16x8*)&Bs[buf][(wc * 32 + i * 16 + l16) * 32 + krow * 8];
#pragma unroll
    for (int mi = 0; mi < 4; mi++)
#pragma unroll
      for (int ni = 0; ni < 2; ni++)
        acc[mi][ni] = __builtin_amdgcn_mfma_f32_16x16x32_bf16(a[mi], b[ni], acc[mi][ni], 0, 0, 0);
  };

  stageG(0, 0);
  __syncthreads();
  for (int k0 = 0; k0 < K; k0 += 64) {
    if (k0 + 32 < K) stageG(1, k0 + 32);
    comp(0);
    __syncthreads();
    if (k0 + 64 < K) stageG(0, k0 + 64);
    comp(1);
    __syncthreads();
  }

#pragma unroll
  for (int mi = 0; mi < 4; mi++)
#pragma unroll
    for (int ni = 0; ni < 2; ni++)
#pragma unroll
      for (int r = 0; r < 4; r++) {
        int row = m0 + wr * 64 + mi * 16 + krow * 4 + r;
        int col = n0 + wc * 32 + ni * 16 + l16;
        float v = acc[mi][ni][r];
        if (OUTBF) ((unsigned short*)C)[(size_t)row * N + col] = f2bf(v);
        else       ((float*)C)[(size_t)row * N + col] = v;
      }
}

// ---------- flash attention (R14: R10/R12 structure + hoisted addresses) ----------
// 8 waves/WG (512 thr), 128 q-rows/WG, 16 q-rows/wave, grid 512 (16 heads x 32 qb).
// LDS 32 KB dbuf K+V -> 16 waves/CU. Swapped QK^T -> lane-local softmax
// (per-lane partial max, defer-max; per-lane partial l reduced in epilogue).
// PV: P^T B-frag = lane's own packed sacc under k-slot perm pi; V A-frag = two
// ds_read_b64 under the same pi. ALL LDS read offsets hoisted to registers;
// buffer select via literal imm offset (0/16384); staging sources are cursors.
__global__ __launch_bounds__(512)
void k_flash(const unsigned short* __restrict__ QKV, const unsigned short* __restrict__ Vt,
             unsigned short* __restrict__ ctx) {
  // shorts: dbuf 2 x (K 4096 | V 4096) = 32 KB
  __shared__ __align__(16) unsigned short LDS[16384];
  const int tid = threadIdx.x, wid = tid >> 6, lane = tid & 63;
  const int l16 = lane & 15, krow = lane >> 4;
  const int bid = blockIdx.x;
  const int swz = (bid & 7) * 64 + (bid >> 3);    // 512 % 8 == 0 -> bijective
  const int head = swz >> 5, qb = swz & 31;       // 2 heads per XCD (K/V/Q ~3MB < 4MB L2)
  const float SC = 0.125f * 1.44269504089f;       // scale into log2 domain

  // Q fragments (B-operand of swapped QK^T): lane holds q-row l16, d = ks*32+krow*8..+7
  bf16x8 qf[2];
#pragma unroll
  for (int ks = 0; ks < 2; ks++) {
    int row = qb * 128 + wid * 16 + l16;
    qf[ks] = *(const bf16x8*)&QKV[(size_t)row * 3072 + head * 64 + ks * 32 + krow * 8];
  }

  // hoisted LDS byte offsets (buf0; buf1 selected by +16384 literal imm)
  unsigned koff[2][4], va0[2][4], va1[2][4];
#pragma unroll
  for (int ks = 0; ks < 2; ks++)
#pragma unroll
    for (int ni = 0; ni < 4; ni++) {
      int row = ni * 16 + l16;
      koff[ks][ni] = row * 128 + (((ks * 4 + krow) ^ (row & 7)) << 4);
      va0[ks][ni] = 8192 + row * 128 + ((krow & 1) << 3)
                  + (((ks * 4 + (krow >> 1)) ^ (row & 7)) << 4);
      va1[ks][ni] = 8192 + row * 128 + ((krow & 1) << 3)
                  + (((ks * 4 + 2 + (krow >> 1)) ^ (row & 7)) << 4);
    }

  // staging source cursors (advance once per staged tile) + fixed LDS dests
  const unsigned short* kSrc;
  const unsigned short* vSrc;
  {
    int row = tid >> 3, sch = (tid & 7) ^ (row & 7);  // pre-swizzled source
    kSrc = QKV + (size_t)row * 3072 + 1024 + head * 64 + sch * 8;
    vSrc = Vt + (size_t)(head * 64 + row) * 4096 + sch * 8;
  }
  char* dK = (char*)LDS + wid * 1024;           // + lane*16 by HW
  char* dV = (char*)LDS + 8192 + wid * 1024;

  f32x4 oaccT[4] = {};      // O^T tiles [di]; col=q(l16), row=d(krow*4+r)
  float mrun = -INFINITY;   // uniform across the 4 krow-lanes of a q
  float lrun = 0.f;         // PER-LANE partial (reduced in epilogue)

  auto stage = [&](const int B) {
    gload_lds16(kSrc, dK + B);
    gload_lds16(vSrc, dV + B);
    kSrc += 64 * 3072;
    vSrc += 64;
  };

  auto body = [&](const int B) {  // B = buf byte offset (0 or 16384), literal
    const char* L = (const char*)LDS;

    // swapped QK^T: sacc[ni] = S^T tile [kv 16][q 16]; lane owns q=l16, kv=ni*16+krow*4+r
    f32x4 sacc[4] = {};
    __builtin_amdgcn_s_setprio(1);
#pragma unroll
    for (int ks = 0; ks < 2; ks++)
#pragma unroll
      for (int ni = 0; ni < 4; ni++) {
        bf16x8 kf = *(const bf16x8*)(L + B + koff[ks][ni]);
        sacc[ni] = __builtin_amdgcn_mfma_f32_16x16x32_bf16(kf, qf[ks], sacc[ni], 0, 0, 0);
      }
    __builtin_amdgcn_s_setprio(0);

    // per-lane partial max over this lane's 16 kv values (raw domain)
    float a = fmax3(sacc[0][0], sacc[0][1], sacc[0][2]);
    a = fmax3(a, sacc[0][3], sacc[1][0]);
    a = fmax3(a, sacc[1][1], sacc[1][2]);
    a = fmax3(a, sacc[1][3], sacc[2][0]);
    a = fmax3(a, sacc[2][1], sacc[2][2]);
    a = fmax3(a, sacc[2][3], sacc[3][0]);
    a = fmax3(a, sacc[3][1], sacc[3][2]);
    a = fmaxf(a, sacc[3][3]);

    // defer-max: cross-lane reduce + rescale only when some lane's partial
    // exceeds the running max by > 8 (log2 domain)
    if (__ballot(__builtin_fmaf(a, SC, -mrun) > 8.f)) {
      a = fmaxf(a, __shfl_xor(a, 16));
      a = fmaxf(a, __shfl_xor(a, 32));      // uniform per q now
      float mnew = fmaxf(mrun, a * SC);
      float al = __builtin_amdgcn_exp2f(mrun - mnew);
      lrun *= al;
      mrun = mnew;
#pragma unroll
      for (int di = 0; di < 4; di++)
#pragma unroll
        for (int r = 0; r < 4; r++) oaccT[di][r] *= al;
    }

    // P = exp2(s*SC - m); per-lane partial row-sum (tree-reduced add chain)
    float ps[4];
#pragma unroll
    for (int ni = 0; ni < 4; ni++) {
      float p0 = __builtin_amdgcn_exp2f(__builtin_fmaf(sacc[ni][0], SC, -mrun));
      float p1 = __builtin_amdgcn_exp2f(__builtin_fmaf(sacc[ni][1], SC, -mrun));
      float p2 = __builtin_amdgcn_exp2f(__builtin_fmaf(sacc[ni][2], SC, -mrun));
      float p3 = __builtin_amdgcn_exp2f(__builtin_fmaf(sacc[ni][3], SC, -mrun));
      sacc[ni][0] = p0; sacc[ni][1] = p1; sacc[ni][2] = p2; sacc[ni][3] = p3;
      ps[ni] = (p0 + p1) + (p2 + p3);
    }
    lrun += (ps[0] + ps[1]) + (ps[2] + ps[3]);

    // B-frags: P^T packed from this lane's OWN sacc under k-slot perm pi:
    //   pi(ks,krow,j) = (2ks + (j>>2))*16 + krow*4 + (j&3)
    union PB { unsigned int w[4]; bf16x8 v; };
    PB pb[2];
#pragma unroll
    for (int ks = 0; ks < 2; ks++) {
      pb[ks].w[0] = pack_trunc(sacc[2 * ks][0],     sacc[2 * ks][1]);
      pb[ks].w[1] = pack_trunc(sacc[2 * ks][2],     sacc[2 * ks][3]);
      pb[ks].w[2] = pack_trunc(sacc[2 * ks + 1][0], sacc[2 * ks + 1][1]);
      pb[ks].w[3] = pack_trunc(sacc[2 * ks + 1][2], sacc[2 * ks + 1][3]);
    }

    // O^T += V^T P^T: A-frag under same pi = two b64 reads (hoisted offsets)
    __builtin_amdgcn_s_setprio(1);
#pragma unroll
    for (int ks = 0; ks < 2; ks++)
#pragma unroll
      for (int di = 0; di < 4; di++) {
        union PB av;
        *(uint2*)&av.w[0] = *(const uint2*)(L + B + va0[ks][di]);
        *(uint2*)&av.w[2] = *(const uint2*)(L + B + va1[ks][di]);
        oaccT[di] = __builtin_amdgcn_mfma_f32_16x16x32_bf16(av.v, pb[ks].v, oaccT[di], 0, 0, 0);
      }
    __builtin_amdgcn_s_setprio(0);
  };

  stage(0);
  __syncthreads();
  for (int kt = 0; kt < 64; kt += 2) {
    stage(16384);
    body(0);
    __syncthreads();           // buf1 staged+drained; all reads of buf0 done
    if (kt + 2 < 64) stage(0);
    body(16384);
    __syncthreads();
  }

  // epilogue: reduce per-lane l partials across the 4 krow-lanes of each q,
  // then per-lane normalize + 8B packed stores
  float lr = lrun;
  lr += __shfl_xor(lr, 16);
  lr += __shfl_xor(lr, 32);
  float li = 1.0f / lr;
  int row = qb * 128 + wid * 16 + l16;
#pragma unroll
  for (int di = 0; di < 4; di++) {
    uint2 w;
    w.x = (unsigned)f2bf(oaccT[di][0] * li) | ((unsigned)f2bf(oaccT[di][1] * li) << 16);
    w.y = (unsigned)f2bf(oaccT[di][2] * li) | ((unsigned)f2bf(oaccT[di][3] * li) << 16);
    *(uint2*)&ctx[(size_t)row * 1024 + head * 64 + di * 16 + krow * 4] = w;
  }
}

// ---------- LN(x + proj_bf16) -> bf16 only ----------
__global__ __launch_bounds__(256)
void k_ln_res(const float* __restrict__ base, const unsigned short* __restrict__ add,
              const float* __restrict__ g, const float* __restrict__ bb,
              unsigned short* __restrict__ outb) {
  const int r = blockIdx.x, tid = threadIdx.x;
  float4 v = ((const float4*)(base + (size_t)r * 1024))[tid];
  {
    u16x4 w = ((const u16x4*)(add + (size_t)r * 1024))[tid];
    v.x += bf2f(w.x); v.y += bf2f(w.y); v.z += bf2f(w.z); v.w += bf2f(w.w);
  }
  float s1 = v.x + v.y + v.z + v.w;
  float s2 = v.x * v.x + v.y * v.y + v.z * v.z + v.w * v.w;
#pragma unroll
  for (int off = 32; off >= 1; off >>= 1) { s1 += __shfl_xor(s1, off); s2 += __shfl_xor(s2, off); }
  __shared__ float red[8];
  if ((tid & 63) == 0) { red[tid >> 6] = s1; red[4 + (tid >> 6)] = s2; }
  __syncthreads();
  s1 = red[0] + red[1] + red[2] + red[3];
  s2 = red[4] + red[5] + red[6] + red[7];
  const float mu = s1 * (1.0f / 1024.0f);
  const float var = s2 * (1.0f / 1024.0f) - mu * mu;
  const float rs = rsqrtf(var + 1e-5f);
  float4 gv = ((const float4*)g)[tid];
  float4 bv = ((const float4*)bb)[tid];
  u16x4 o;
  o.x = f2bf((v.x - mu) * rs * gv.x + bv.x);
  o.y = f2bf((v.y - mu) * rs * gv.y + bv.y);
  o.z = f2bf((v.z - mu) * rs * gv.z + bv.z);
  o.w = f2bf((v.w - mu) * rs * gv.w + bv.w);
  ((u16x4*)(outb + (size_t)r * 1024))[tid] = o;
}

// ---------- relu(LN(lin_bf16 + out_b + mha_bf16)) -> fp32 out ----------
__global__ __launch_bounds__(256)
void k_ln2(const unsigned short* __restrict__ lin, const unsigned short* __restrict__ mha,
           const float* __restrict__ ob, const float* __restrict__ g,
           const float* __restrict__ bb, float* __restrict__ out) {
  const int r = blockIdx.x, tid = threadIdx.x;
  float4 v;
  {
    u16x4 a = ((const u16x4*)(lin + (size_t)r * 1024))[tid];
    u16x4 w = ((const u16x4*)(mha + (size_t)r * 1024))[tid];
    float4 o = ((const float4*)ob)[tid];
    v.x = bf2f(a.x) + bf2f(w.x) + o.x;
    v.y = bf2f(a.y) + bf2f(w.y) + o.y;
    v.z = bf2f(a.z) + bf2f(w.z) + o.z;
    v.w = bf2f(a.w) + bf2f(w.w) + o.w;
  }
  float s1 = v.x + v.y + v.z + v.w;
  float s2 = v.x * v.x + v.y * v.y + v.z * v.z + v.w * v.w;
#pragma unroll
  for (int off = 32; off >= 1; off >>= 1) { s1 += __shfl_xor(s1, off); s2 += __shfl_xor(s2, off); }
  __shared__ float red[8];
  if ((tid & 63) == 0) { red[tid >> 6] = s1; red[4 + (tid >> 6)] = s2; }
  __syncthreads();
  s1 = red[0] + red[1] + red[2] + red[3];
  s2 = red[4] + red[5] + red[6] + red[7];
  const float mu = s1 * (1.0f / 1024.0f);
  const float var = s2 * (1.0f / 1024.0f) - mu * mu;
  const float rs = rsqrtf(var + 1e-5f);
  float4 gv = ((const float4*)g)[tid];
  float4 bv = ((const float4*)bb)[tid];
  float4 y;
  y.x = fmaxf(0.f, (v.x - mu) * rs * gv.x + bv.x);
  y.y = fmaxf(0.f, (v.y - mu) * rs * gv.y + bv.y);
  y.z = fmaxf(0.f, (v.z - mu) * rs * gv.z + bv.z);
  y.w = fmaxf(0.f, (v.w - mu) * rs * gv.w + bv.w);
  ((float4*)(out + (size_t)r * 1024))[tid] = y;
}

// ---------- launch ----------
extern "C" void kernel_launch(void* const* d_in, const int* in_sizes, int n_in,
                              void* d_out, int out_size, void* d_ws, size_t ws_size,
                              hipStream_t stream) {
  (void)in_sizes; (void)n_in; (void)out_size; (void)ws_size;
  const float* x     = (const float*)d_in[0];
  const float* Wq    = (const float*)d_in[1];
  const float* Wk    = (const float*)d_in[2];
  const float* Wv    = (const float*)d_in[3];
  const float* Wo    = (const float*)d_in[4];
  const float* out_w = (const float*)d_in[5];
  const float* out_b = (const float*)d_in[6];
  const float* g1    = (const float*)d_in[7];
  const float* b1    = (const float*)d_in[8];
  const float* g2    = (const float*)d_in[9];
  const float* b2    = (const float*)d_in[10];
  float* out = (float*)d_out;

  // workspace layout (aliased; 60 MB total, liveness-checked)
  const size_t MB = 1ull << 20;
  char* ws = (char*)d_ws;
  unsigned short* xb    = (unsigned short*)(ws + 0);        // [4096][1024] bf16   (dead after GEMM1)
  unsigned short* WqkvT = (unsigned short*)(ws + 8 * MB);   // [3072][1024] bf16   (dead after GEMM1)
  unsigned short* OwB   = (unsigned short*)(ws + 16 * MB);  // out_w bf16 [1024][1024]
  unsigned short* QKV   = (unsigned short*)(ws + 18 * MB);  // [4096][3072] bf16 (Q,K used; V cols unwritten)
  unsigned short* Vt    = (unsigned short*)(ws + 42 * MB);  // [1024][4096] bf16   (dead after attn)
  unsigned short* ctx   = (unsigned short*)(ws + 50 * MB);  // [4096][1024] bf16   (dead after GEMM2)
  unsigned short* WoT   = (unsigned short*)(ws + 58 * MB);  // W_o^T bf16
  unsigned short* proj  = (unsigned short*)(ws + 0);        // [4096][1024] bf16 (over xb)
  unsigned short* mhaB  = (unsigned short*)(ws + 34 * MB);  // [4096][1024] bf16 (over QKV tail)
  unsigned short* lin   = (unsigned short*)(ws + 42 * MB);  // [4096][1024] bf16 (over Vt)

  k_prep<<<9216, 256, 0, stream>>>(x, xb, out_w, OwB, Wq, Wk, Wv, Wo, WqkvT, WoT);

  // GEMM1: QKV projection; V columns (n0>=2048) stream transposed into Vt
  k_gemm_bt<2><<<dim3(32, 24), 256, 0, stream>>>(xb, WqkvT, QKV, Vt, 4096, 3072, 1024);
  k_flash<<<512, 512, 0, stream>>>(QKV, Vt, ctx);
  k_gemm_bt_n64<1><<<dim3(32, 16), 256, 0, stream>>>(ctx, WoT, proj, 4096, 1024, 1024);
  k_ln_res<<<4096, 256, 0, stream>>>(x, proj, g1, b1, mhaB);
  k_gemm_bt_n64<1><<<dim3(32, 16), 256, 0, stream>>>(mhaB, OwB, lin, 4096, 1024, 1024);
  k_ln2<<<4096, 256, 0, stream>>>(lin, mhaB, out_b, g2, b2, out);
}

// Round 16
// 185.983 us; speedup vs baseline: 1.2025x; 1.0075x over previous
//
#include <hip/hip_runtime.h>
#include <cstdint>
#include <math.h>

// ---------- types ----------
typedef __attribute__((ext_vector_type(8))) short bf16x8;   // MFMA A/B operand (4 VGPRs)
typedef __attribute__((ext_vector_type(4))) float f32x4;    // MFMA C/D operand
typedef __attribute__((ext_vector_type(4))) unsigned short u16x4;

__device__ __forceinline__ unsigned short f2bf(float f) {
  union { float f; unsigned int u; } c; c.f = f;
  unsigned int u = c.u;
  return (unsigned short)((u + 0x7FFFu + ((u >> 16) & 1u)) >> 16);  // RNE
}
__device__ __forceinline__ float bf2f(unsigned short u) {
  return __uint_as_float(((unsigned int)u) << 16);
}

// pack hi16(a) | hi16(b)<<16 via v_perm_b32 (1 VALU op; trunc-to-bf16)
__device__ __forceinline__ unsigned int pack_trunc(float a, float b) {
  return __builtin_amdgcn_perm(__float_as_uint(b), __float_as_uint(a), 0x07060302u);
}

__device__ __forceinline__ float fmax3(float a, float b, float c) {
  return fmaxf(fmaxf(a, b), c);  // clang fuses to v_max3_f32
}

__device__ __forceinline__ void gload_lds16(const void* g, void* l) {
  __builtin_amdgcn_global_load_lds(
      (const __attribute__((address_space(1))) unsigned int*)g,
      (__attribute__((address_space(3))) unsigned int*)l, 16, 0, 0);
}

// counted-vmcnt barrier (T4): wait only the oldest loads, never full drain
#define FSYNC(N) do {                                        \
    asm volatile("s_waitcnt vmcnt(" N ")" ::: "memory");     \
    __builtin_amdgcn_s_barrier();                            \
    __builtin_amdgcn_sched_barrier(0);                       \
  } while (0)

// ---------- prep: weight transposes (blocks 0..4095) + fp32->bf16 converts ----------
__global__ __launch_bounds__(256)
void k_prep(const float* __restrict__ x, unsigned short* __restrict__ xb,
            const float* __restrict__ out_w, unsigned short* __restrict__ OwB,
            const float* __restrict__ w0, const float* __restrict__ w1,
            const float* __restrict__ w2, const float* __restrict__ w3,
            unsigned short* __restrict__ o012, unsigned short* __restrict__ o3) {
  __shared__ float t[32][33];
  const int b = blockIdx.x;
  if (b < 4096) {
    const int m = b >> 10, rem = b & 1023;
    const float* in = m == 0 ? w0 : m == 1 ? w1 : m == 2 ? w2 : w3;
    unsigned short* out = m < 3 ? o012 + (size_t)m * 1048576 : o3;
    const int r0 = (rem >> 5) << 5, c0 = (rem & 31) << 5;
    const int tx = threadIdx.x & 31, ty = threadIdx.x >> 5;  // 32 x 8
#pragma unroll
    for (int rr = ty; rr < 32; rr += 8) t[rr][tx] = in[(size_t)(r0 + rr) * 1024 + c0 + tx];
    __syncthreads();
#pragma unroll
    for (int cc = ty; cc < 32; cc += 8)
      out[(size_t)(c0 + cc) * 1024 + r0 + tx] = f2bf(t[tx][cc]);
  } else {
    int i = (b - 4096) * 256 + threadIdx.x;
    const float* in;
    unsigned short* out;
    if (i < 1048576) { in = x; out = xb; }
    else { i -= 1048576; if (i >= 262144) return; in = out_w; out = OwB; }
    float4 v = ((const float4*)in)[i];
    u16x4 o;
    o.x = f2bf(v.x); o.y = f2bf(v.y); o.z = f2bf(v.z); o.w = f2bf(v.w);
    ((u16x4*)out)[i] = o;
  }
}

// ---------- bf16 GEMM 128x128, dbuf + 1 barrier/K-step (T3-min) ----------
// MODE 0: fp32 C.  MODE 1: bf16 C.  MODE 2: bf16 C for n0<VCOL0; cols >= VCOL0
// are written TRANSPOSED to VT[col-VCOL0][row] (fused V-transpose for attention).
template <int MODE>
__global__ __launch_bounds__(256)
void k_gemm_bt(const unsigned short* __restrict__ A, const unsigned short* __restrict__ BT,
               void* __restrict__ C, unsigned short* __restrict__ VT,
               int M, int N, int K) {
  const int VCOL0 = 2048;
  __shared__ __align__(16) unsigned short As[2][128 * 32];
  __shared__ __align__(16) unsigned short Bs[2][128 * 32];
  const int tid = threadIdx.x;
  const int wid = tid >> 6, lane = tid & 63;
  const int l16 = lane & 15, krow = lane >> 4;
  const int m0 = blockIdx.x * 128, n0 = blockIdx.y * 128;
  const int wr = wid >> 1, wc = wid & 1;  // 2x2 waves, 64x64 each

  f32x4 acc[4][4] = {};

  auto stageG = [&](int buf, int k0) {
#pragma unroll
    for (int j = 0; j < 2; j++) {
      int f = j * 256 + tid;
      gload_lds16(A  + (size_t)(m0 + (f >> 2)) * K + k0 + (f & 3) * 8,
                  (char*)As[buf] + (size_t)(j * 256 + wid * 64) * 16);
      gload_lds16(BT + (size_t)(n0 + (f >> 2)) * K + k0 + (f & 3) * 8,
                  (char*)Bs[buf] + (size_t)(j * 256 + wid * 64) * 16);
    }
  };
  auto comp = [&](int buf) {
    bf16x8 a[4], b[4];
#pragma unroll
    for (int i = 0; i < 4; i++) {
      a[i] = *(const bf16x8*)&As[buf][(wr * 64 + i * 16 + l16) * 32 + krow * 8];
      b[i] = *(const bf16x8*)&Bs[buf][(wc * 64 + i * 16 + l16) * 32 + krow * 8];
    }
#pragma unroll
    for (int mi = 0; mi < 4; mi++)
#pragma unroll
      for (int ni = 0; ni < 4; ni++)
        acc[mi][ni] = __builtin_amdgcn_mfma_f32_16x16x32_bf16(a[mi], b[ni], acc[mi][ni], 0, 0, 0);
  };

  stageG(0, 0);
  __syncthreads();
  for (int k0 = 0; k0 < K; k0 += 64) {
    if (k0 + 32 < K) stageG(1, k0 + 32);
    comp(0);
    __syncthreads();
    if (k0 + 64 < K) stageG(0, k0 + 64);
    comp(1);
    __syncthreads();
  }

  if (MODE == 2 && n0 >= VCOL0) {
    // V region: write transposed to VT[col - VCOL0][row] (rows consecutive per lane)
#pragma unroll
    for (int mi = 0; mi < 4; mi++)
#pragma unroll
      for (int ni = 0; ni < 4; ni++) {
        int col = n0 - VCOL0 + wc * 64 + ni * 16 + l16;
        int row = m0 + wr * 64 + mi * 16 + krow * 4;
        uint2 w;
        w.x = (unsigned)f2bf(acc[mi][ni][0]) | ((unsigned)f2bf(acc[mi][ni][1]) << 16);
        w.y = (unsigned)f2bf(acc[mi][ni][2]) | ((unsigned)f2bf(acc[mi][ni][3]) << 16);
        *(uint2*)&VT[(size_t)col * 4096 + row] = w;
      }
    return;
  }

#pragma unroll
  for (int mi = 0; mi < 4; mi++)
#pragma unroll
    for (int ni = 0; ni < 4; ni++)
#pragma unroll
      for (int r = 0; r < 4; r++) {
        int row = m0 + wr * 64 + mi * 16 + krow * 4 + r;
        int col = n0 + wc * 64 + ni * 16 + l16;
        float v = acc[mi][ni][r];
        if (MODE) ((unsigned short*)C)[(size_t)row * N + col] = f2bf(v);
        else      ((float*)C)[(size_t)row * N + col] = v;
      }
}

// ---------- bf16 GEMM 128x64, dbuf + 1 barrier/K-step ----------
template <int OUTBF>
__global__ __launch_bounds__(256)
void k_gemm_bt_n64(const unsigned short* __restrict__ A, const unsigned short* __restrict__ BT,
                   void* __restrict__ C, int M, int N, int K) {
  __shared__ __align__(16) unsigned short As[2][128 * 32];
  __shared__ __align__(16) unsigned short Bs[2][64 * 32];
  const int tid = threadIdx.x;
  const int wid = tid >> 6, lane = tid & 63;
  const int l16 = lane & 15, krow = lane >> 4;
  const int m0 = blockIdx.x * 128, n0 = blockIdx.y * 64;
  const int wr = wid >> 1, wc = wid & 1;  // 2x2 waves, 64x32 each

  f32x4 acc[4][2] = {};

  auto stageG = [&](int buf, int k0) {
#pragma unroll
    for (int j = 0; j < 2; j++) {
      int f = j * 256 + tid;
      gload_lds16(A + (size_t)(m0 + (f >> 2)) * K + k0 + (f & 3) * 8,
                  (char*)As[buf] + (size_t)(j * 256 + wid * 64) * 16);
    }
    gload_lds16(BT + (size_t)(n0 + (tid >> 2)) * K + k0 + (tid & 3) * 8,
                (char*)Bs[buf] + (size_t)(wid * 64) * 16);
  };
  auto comp = [&](int buf) {
    bf16x8 a[4], b[2];
#pragma unroll
    for (int i = 0; i < 4; i++)
      a[i] = *(const bf16x8*)&As[buf][(wr * 64 + i * 16 + l16) * 32 + krow * 8];
#pragma unroll
    for (int i = 0; i < 2; i++)
      b[i] = *(const bf16x8*)&Bs[buf][(wc * 32 + i * 16 + l16) * 32 + krow * 8];
#pragma unroll
    for (int mi = 0; mi < 4; mi++)
#pragma unroll
      for (int ni = 0; ni < 2; ni++)
        acc[mi][ni] = __builtin_amdgcn_mfma_f32_16x16x32_bf16(a[mi], b[ni], acc[mi][ni], 0, 0, 0);
  };

  stageG(0, 0);
  __syncthreads();
  for (int k0 = 0; k0 < K; k0 += 64) {
    if (k0 + 32 < K) stageG(1, k0 + 32);
    comp(0);
    __syncthreads();
    if (k0 + 64 < K) stageG(0, k0 + 64);
    comp(1);
    __syncthreads();
  }

#pragma unroll
  for (int mi = 0; mi < 4; mi++)
#pragma unroll
    for (int ni = 0; ni < 2; ni++)
#pragma unroll
      for (int r = 0; r < 4; r++) {
        int row = m0 + wr * 64 + mi * 16 + krow * 4 + r;
        int col = n0 + wc * 32 + ni * 16 + l16;
        float v = acc[mi][ni][r];
        if (OUTBF) ((unsigned short*)C)[(size_t)row * N + col] = f2bf(v);
        else       ((float*)C)[(size_t)row * N + col] = v;
      }
}

// ---------- flash attention (R14 body + 4-slot counted-vmcnt pipeline, T3/T4) ----------
// 8 waves/WG (512 thr), 128 q-rows/WG, 16 q-rows/wave, grid 512 (16 heads x 32 qb).
// LDS 64 KB: 4 slots x (K 8KB | V 8KB) -> 2 WG/CU = 16 waves/CU. Prefetch depth 3;
// per tile-step: s_waitcnt vmcnt(4) (retire oldest tile only) + raw s_barrier,
// then stage tile t+3. Never drains vmcnt to 0 in steady state (T4, m218).
__global__ __launch_bounds__(512)
void k_flash(const unsigned short* __restrict__ QKV, const unsigned short* __restrict__ Vt,
             unsigned short* __restrict__ ctx) {
  // shorts: 4 slots x 8192 (K 4096 | V 4096 each)
  __shared__ __align__(16) unsigned short LDS[32768];
  const int tid = threadIdx.x, wid = tid >> 6, lane = tid & 63;
  const int l16 = lane & 15, krow = lane >> 4;
  const int bid = blockIdx.x;
  const int swz = (bid & 7) * 64 + (bid >> 3);    // 512 % 8 == 0 -> bijective
  const int head = swz >> 5, qb = swz & 31;       // 2 heads per XCD (K/V/Q ~3MB < 4MB L2)
  const float SC = 0.125f * 1.44269504089f;       // scale into log2 domain

  // Q fragments (B-operand of swapped QK^T): lane holds q-row l16, d = ks*32+krow*8..+7
  bf16x8 qf[2];
#pragma unroll
  for (int ks = 0; ks < 2; ks++) {
    int row = qb * 128 + wid * 16 + l16;
    qf[ks] = *(const bf16x8*)&QKV[(size_t)row * 3072 + head * 64 + ks * 32 + krow * 8];
  }

  // hoisted LDS byte offsets (slot 0; other slots via literal +16384k)
  unsigned koff[2][4], va0[2][4], va1[2][4];
#pragma unroll
  for (int ks = 0; ks < 2; ks++)
#pragma unroll
    for (int ni = 0; ni < 4; ni++) {
      int row = ni * 16 + l16;
      koff[ks][ni] = row * 128 + (((ks * 4 + krow) ^ (row & 7)) << 4);
      va0[ks][ni] = 8192 + row * 128 + ((krow & 1) << 3)
                  + (((ks * 4 + (krow >> 1)) ^ (row & 7)) << 4);
      va1[ks][ni] = 8192 + row * 128 + ((krow & 1) << 3)
                  + (((ks * 4 + 2 + (krow >> 1)) ^ (row & 7)) << 4);
    }

  // staging source cursors (advance once per staged tile) + fixed LDS dests
  const unsigned short* kSrc;
  const unsigned short* vSrc;
  {
    int row = tid >> 3, sch = (tid & 7) ^ (row & 7);  // pre-swizzled source
    kSrc = QKV + (size_t)row * 3072 + 1024 + head * 64 + sch * 8;
    vSrc = Vt + (size_t)(head * 64 + row) * 4096 + sch * 8;
  }
  char* dK = (char*)LDS + wid * 1024;           // + lane*16 by HW
  char* dV = (char*)LDS + 8192 + wid * 1024;

  f32x4 oaccT[4] = {};      // O^T tiles [di]; col=q(l16), row=d(krow*4+r)
  float mrun = -INFINITY;   // uniform across the 4 krow-lanes of a q
  float lrun = 0.f;         // PER-LANE partial (reduced in epilogue)

  auto stage = [&](const int B) {   // B = slot byte offset, literal
    gload_lds16(kSrc, dK + B);
    gload_lds16(vSrc, dV + B);
    kSrc += 64 * 3072;
    vSrc += 64;
  };

  auto body = [&](const int B) {  // B = slot byte offset, literal
    const char* L = (const char*)LDS;

    // swapped QK^T: sacc[ni] = S^T tile [kv 16][q 16]; lane owns q=l16, kv=ni*16+krow*4+r
    f32x4 sacc[4] = {};
    __builtin_amdgcn_s_setprio(1);
#pragma unroll
    for (int ks = 0; ks < 2; ks++)
#pragma unroll
      for (int ni = 0; ni < 4; ni++) {
        bf16x8 kf = *(const bf16x8*)(L + B + koff[ks][ni]);
        sacc[ni] = __builtin_amdgcn_mfma_f32_16x16x32_bf16(kf, qf[ks], sacc[ni], 0, 0, 0);
      }
    __builtin_amdgcn_s_setprio(0);

    // per-lane partial max over this lane's 16 kv values (raw domain)
    float a = fmax3(sacc[0][0], sacc[0][1], sacc[0][2]);
    a = fmax3(a, sacc[0][3], sacc[1][0]);
    a = fmax3(a, sacc[1][1], sacc[1][2]);
    a = fmax3(a, sacc[1][3], sacc[2][0]);
    a = fmax3(a, sacc[2][1], sacc[2][2]);
    a = fmax3(a, sacc[2][3], sacc[3][0]);
    a = fmax3(a, sacc[3][1], sacc[3][2]);
    a = fmaxf(a, sacc[3][3]);

    // defer-max: cross-lane reduce + rescale only when some lane's partial
    // exceeds the running max by > 8 (log2 domain)
    if (__ballot(__builtin_fmaf(a, SC, -mrun) > 8.f)) {
      a = fmaxf(a, __shfl_xor(a, 16));
      a = fmaxf(a, __shfl_xor(a, 32));      // uniform per q now
      float mnew = fmaxf(mrun, a * SC);
      float al = __builtin_amdgcn_exp2f(mrun - mnew);
      lrun *= al;
      mrun = mnew;
#pragma unroll
      for (int di = 0; di < 4; di++)
#pragma unroll
        for (int r = 0; r < 4; r++) oaccT[di][r] *= al;
    }

    // P = exp2(s*SC - m); per-lane partial row-sum (tree-reduced add chain)
    float ps[4];
#pragma unroll
    for (int ni = 0; ni < 4; ni++) {
      float p0 = __builtin_amdgcn_exp2f(__builtin_fmaf(sacc[ni][0], SC, -mrun));
      float p1 = __builtin_amdgcn_exp2f(__builtin_fmaf(sacc[ni][1], SC, -mrun));
      float p2 = __builtin_amdgcn_exp2f(__builtin_fmaf(sacc[ni][2], SC, -mrun));
      float p3 = __builtin_amdgcn_exp2f(__builtin_fmaf(sacc[ni][3], SC, -mrun));
      sacc[ni][0] = p0; sacc[ni][1] = p1; sacc[ni][2] = p2; sacc[ni][3] = p3;
      ps[ni] = (p0 + p1) + (p2 + p3);
    }
    lrun += (ps[0] + ps[1]) + (ps[2] + ps[3]);

    // B-frags: P^T packed from this lane's OWN sacc under k-slot perm pi:
    //   pi(ks,krow,j) = (2ks + (j>>2))*16 + krow*4 + (j&3)
    union PB { unsigned int w[4]; bf16x8 v; };
    PB pb[2];
#pragma unroll
    for (int ks = 0; ks < 2; ks++) {
      pb[ks].w[0] = pack_trunc(sacc[2 * ks][0],     sacc[2 * ks][1]);
      pb[ks].w[1] = pack_trunc(sacc[2 * ks][2],     sacc[2 * ks][3]);
      pb[ks].w[2] = pack_trunc(sacc[2 * ks + 1][0], sacc[2 * ks + 1][1]);
      pb[ks].w[3] = pack_trunc(sacc[2 * ks + 1][2], sacc[2 * ks + 1][3]);
    }

    // O^T += V^T P^T: A-frag under same pi = two b64 reads (hoisted offsets)
    __builtin_amdgcn_s_setprio(1);
#pragma unroll
    for (int ks = 0; ks < 2; ks++)
#pragma unroll
      for (int di = 0; di < 4; di++) {
        union PB av;
        *(uint2*)&av.w[0] = *(const uint2*)(L + B + va0[ks][di]);
        *(uint2*)&av.w[2] = *(const uint2*)(L + B + va1[ks][di]);
        oaccT[di] = __builtin_amdgcn_mfma_f32_16x16x32_bf16(av.v, pb[ks].v, oaccT[di], 0, 0, 0);
      }
    __builtin_amdgcn_s_setprio(0);
  };

  // prologue: stage tiles 0,1,2 into slots 0,1,2 (6 loads in flight; cursor-ordered)
  stage(0);
  stage(16384);
  stage(32768);

  // steps t=0..59 (15 x 4 unroll, literal slots). Invariant at step t: tiles
  // t,t+1,t+2 staged (6 outstanding; t's 2 loads oldest). vmcnt(4) retires t.
  for (int t = 0; t < 60; t += 4) {
    FSYNC("4"); stage(49152); body(0);      // body tile t   (slot 0), stage t+3 (slot 3)
    FSYNC("4"); stage(0);     body(16384);  // body tile t+1 (slot 1), stage t+4 (slot 0)
    FSYNC("4"); stage(16384); body(32768);  // body tile t+2 (slot 2), stage t+5 (slot 1)
    FSYNC("4"); stage(32768); body(49152);  // body tile t+3 (slot 3), stage t+6 (slot 2)
  }
  // tail t=60..63: stage tile 63 at t=60; drain 4 -> 4 -> 2 -> 0
  FSYNC("4"); stage(49152); body(0);        // t=60 (slot 0), stage 63 (slot 3)
  FSYNC("4"); body(16384);                  // t=61 (slot 1)
  FSYNC("2"); body(32768);                  // t=62 (slot 2)
  FSYNC("0"); body(49152);                  // t=63 (slot 3)

  // epilogue: reduce per-lane l partials across the 4 krow-lanes of each q,
  // then per-lane normalize + 8B packed stores
  float lr = lrun;
  lr += __shfl_xor(lr, 16);
  lr += __shfl_xor(lr, 32);
  float li = 1.0f / lr;
  int row = qb * 128 + wid * 16 + l16;
#pragma unroll
  for (int di = 0; di < 4; di++) {
    uint2 w;
    w.x = (unsigned)f2bf(oaccT[di][0] * li) | ((unsigned)f2bf(oaccT[di][1] * li) << 16);
    w.y = (unsigned)f2bf(oaccT[di][2] * li) | ((unsigned)f2bf(oaccT[di][3] * li) << 16);
    *(uint2*)&ctx[(size_t)row * 1024 + head * 64 + di * 16 + krow * 4] = w;
  }
}

// ---------- LN(x + proj_bf16) -> bf16 only ----------
__global__ __launch_bounds__(256)
void k_ln_res(const float* __restrict__ base, const unsigned short* __restrict__ add,
              const float* __restrict__ g, const float* __restrict__ bb,
              unsigned short* __restrict__ outb) {
  const int r = blockIdx.x, tid = threadIdx.x;
  float4 v = ((const float4*)(base + (size_t)r * 1024))[tid];
  {
    u16x4 w = ((const u16x4*)(add + (size_t)r * 1024))[tid];
    v.x += bf2f(w.x); v.y += bf2f(w.y); v.z += bf2f(w.z); v.w += bf2f(w.w);
  }
  float s1 = v.x + v.y + v.z + v.w;
  float s2 = v.x * v.x + v.y * v.y + v.z * v.z + v.w * v.w;
#pragma unroll
  for (int off = 32; off >= 1; off >>= 1) { s1 += __shfl_xor(s1, off); s2 += __shfl_xor(s2, off); }
  __shared__ float red[8];
  if ((tid & 63) == 0) { red[tid >> 6] = s1; red[4 + (tid >> 6)] = s2; }
  __syncthreads();
  s1 = red[0] + red[1] + red[2] + red[3];
  s2 = red[4] + red[5] + red[6] + red[7];
  const float mu = s1 * (1.0f / 1024.0f);
  const float var = s2 * (1.0f / 1024.0f) - mu * mu;
  const float rs = rsqrtf(var + 1e-5f);
  float4 gv = ((const float4*)g)[tid];
  float4 bv = ((const float4*)bb)[tid];
  u16x4 o;
  o.x = f2bf((v.x - mu) * rs * gv.x + bv.x);
  o.y = f2bf((v.y - mu) * rs * gv.y + bv.y);
  o.z = f2bf((v.z - mu) * rs * gv.z + bv.z);
  o.w = f2bf((v.w - mu) * rs * gv.w + bv.w);
  ((u16x4*)(outb + (size_t)r * 1024))[tid] = o;
}

// ---------- relu(LN(lin_bf16 + out_b + mha_bf16)) -> fp32 out ----------
__global__ __launch_bounds__(256)
void k_ln2(const unsigned short* __restrict__ lin, const unsigned short* __restrict__ mha,
           const float* __restrict__ ob, const float* __restrict__ g,
           const float* __restrict__ bb, float* __restrict__ out) {
  const int r = blockIdx.x, tid = threadIdx.x;
  float4 v;
  {
    u16x4 a = ((const u16x4*)(lin + (size_t)r * 1024))[tid];
    u16x4 w = ((const u16x4*)(mha + (size_t)r * 1024))[tid];
    float4 o = ((const float4*)ob)[tid];
    v.x = bf2f(a.x) + bf2f(w.x) + o.x;
    v.y = bf2f(a.y) + bf2f(w.y) + o.y;
    v.z = bf2f(a.z) + bf2f(w.z) + o.z;
    v.w = bf2f(a.w) + bf2f(w.w) + o.w;
  }
  float s1 = v.x + v.y + v.z + v.w;
  float s2 = v.x * v.x + v.y * v.y + v.z * v.z + v.w * v.w;
#pragma unroll
  for (int off = 32; off >= 1; off >>= 1) { s1 += __shfl_xor(s1, off); s2 += __shfl_xor(s2, off); }
  __shared__ float red[8];
  if ((tid & 63) == 0) { red[tid >> 6] = s1; red[4 + (tid >> 6)] = s2; }
  __syncthreads();
  s1 = red[0] + red[1] + red[2] + red[3];
  s2 = red[4] + red[5] + red[6] + red[7];
  const float mu = s1 * (1.0f / 1024.0f);
  const float var = s2 * (1.0f / 1024.0f) - mu * mu;
  const float rs = rsqrtf(var + 1e-5f);
  float4 gv = ((const float4*)g)[tid];
  float4 bv = ((const float4*)bb)[tid];
  float4 y;
  y.x = fmaxf(0.f, (v.x - mu) * rs * gv.x + bv.x);
  y.y = fmaxf(0.f, (v.y - mu) * rs * gv.y + bv.y);
  y.z = fmaxf(0.f, (v.z - mu) * rs * gv.z + bv.z);
  y.w = fmaxf(0.f, (v.w - mu) * rs * gv.w + bv.w);
  ((float4*)(out + (size_t)r * 1024))[tid] = y;
}

// ---------- launch ----------
extern "C" void kernel_launch(void* const* d_in, const int* in_sizes, int n_in,
                              void* d_out, int out_size, void* d_ws, size_t ws_size,
                              hipStream_t stream) {
  (void)in_sizes; (void)n_in; (void)out_size; (void)ws_size;
  const float* x     = (const float*)d_in[0];
  const float* Wq    = (const float*)d_in[1];
  const float* Wk    = (const float*)d_in[2];
  const float* Wv    = (const float*)d_in[3];
  const float* Wo    = (const float*)d_in[4];
  const float* out_w = (const float*)d_in[5];
  const float* out_b = (const float*)d_in[6];
  const float* g1    = (const float*)d_in[7];
  const float* b1    = (const float*)d_in[8];
  const float* g2    = (const float*)d_in[9];
  const float* b2    = (const float*)d_in[10];
  float* out = (float*)d_out;

  // workspace layout (aliased; 60 MB total, liveness-checked)
  const size_t MB = 1ull << 20;
  char* ws = (char*)d_ws;
  unsigned short* xb    = (unsigned short*)(ws + 0);        // [4096][1024] bf16   (dead after GEMM1)
  unsigned short* WqkvT = (unsigned short*)(ws + 8 * MB);   // [3072][1024] bf16   (dead after GEMM1)
  unsigned short* OwB   = (unsigned short*)(ws + 16 * MB);  // out_w bf16 [1024][1024]
  unsigned short* QKV   = (unsigned short*)(ws + 18 * MB);  // [4096][3072] bf16 (Q,K used; V cols unwritten)
  unsigned short* Vt    = (unsigned short*)(ws + 42 * MB);  // [1024][4096] bf16   (dead after attn)
  unsigned short* ctx   = (unsigned short*)(ws + 50 * MB);  // [4096][1024] bf16   (dead after GEMM2)
  unsigned short* WoT   = (unsigned short*)(ws + 58 * MB);  // W_o^T bf16
  unsigned short* proj  = (unsigned short*)(ws + 0);        // [4096][1024] bf16 (over xb)
  unsigned short* mhaB  = (unsigned short*)(ws + 34 * MB);  // [4096][1024] bf16 (over QKV tail)
  unsigned short* lin   = (unsigned short*)(ws + 42 * MB);  // [4096][1024] bf16 (over Vt)

  k_prep<<<9216, 256, 0, stream>>>(x, xb, out_w, OwB, Wq, Wk, Wv, Wo, WqkvT, WoT);

  // GEMM1: QKV projection; V columns (n0>=2048) stream transposed into Vt
  k_gemm_bt<2><<<dim3(32, 24), 256, 0, stream>>>(xb, WqkvT, QKV, Vt, 4096, 3072, 1024);
  k_flash<<<512, 512, 0, stream>>>(QKV, Vt, ctx);
  k_gemm_bt_n64<1><<<dim3(32, 16), 256, 0, stream>>>(ctx, WoT, proj, 4096, 1024, 1024);
  k_ln_res<<<4096, 256, 0, stream>>>(x, proj, g1, b1, mhaB);
  k_gemm_bt_n64<1><<<dim3(32, 16), 256, 0, stream>>>(mhaB, OwB, lin, 4096, 1024, 1024);
  k_ln2<<<4096, 256, 0, stream>>>(lin, mhaB, out_b, g2, b2, out);
}

// Round 17
// 179.591 us; speedup vs baseline: 1.2453x; 1.0356x over previous
//
#include <hip/hip_runtime.h>
#include <cstdint>
#include <math.h>

// ---------- types ----------
typedef __attribute__((ext_vector_type(8))) short bf16x8;   // MFMA A/B operand (4 VGPRs)
typedef __attribute__((ext_vector_type(4))) float f32x4;    // MFMA C/D operand
typedef __attribute__((ext_vector_type(4))) unsigned short u16x4;

__device__ __forceinline__ unsigned short f2bf(float f) {
  union { float f; unsigned int u; } c; c.f = f;
  unsigned int u = c.u;
  return (unsigned short)((u + 0x7FFFu + ((u >> 16) & 1u)) >> 16);  // RNE
}
__device__ __forceinline__ float bf2f(unsigned short u) {
  return __uint_as_float(((unsigned int)u) << 16);
}

// pack hi16(a) | hi16(b)<<16 via v_perm_b32 (1 VALU op; trunc-to-bf16)
__device__ __forceinline__ unsigned int pack_trunc(float a, float b) {
  return __builtin_amdgcn_perm(__float_as_uint(b), __float_as_uint(a), 0x07060302u);
}

__device__ __forceinline__ float fmax3(float a, float b, float c) {
  return fmaxf(fmaxf(a, b), c);  // clang fuses to v_max3_f32
}

__device__ __forceinline__ void gload_lds16(const void* g, void* l) {
  __builtin_amdgcn_global_load_lds(
      (const __attribute__((address_space(1))) unsigned int*)g,
      (__attribute__((address_space(3))) unsigned int*)l, 16, 0, 0);
}

// counted-vmcnt barrier (T4): wait only the oldest loads, never full drain
#define FSYNC(N) do {                                        \
    asm volatile("s_waitcnt vmcnt(" N ")" ::: "memory");     \
    __builtin_amdgcn_s_barrier();                            \
    __builtin_amdgcn_sched_barrier(0);                       \
  } while (0)

// ---------- prep: weight transposes (blocks 0..4095) + fp32->bf16 converts ----------
__global__ __launch_bounds__(256)
void k_prep(const float* __restrict__ x, unsigned short* __restrict__ xb,
            const float* __restrict__ out_w, unsigned short* __restrict__ OwB,
            const float* __restrict__ w0, const float* __restrict__ w1,
            const float* __restrict__ w2, const float* __restrict__ w3,
            unsigned short* __restrict__ o012, unsigned short* __restrict__ o3) {
  __shared__ float t[32][33];
  const int b = blockIdx.x;
  if (b < 4096) {
    const int m = b >> 10, rem = b & 1023;
    const float* in = m == 0 ? w0 : m == 1 ? w1 : m == 2 ? w2 : w3;
    unsigned short* out = m < 3 ? o012 + (size_t)m * 1048576 : o3;
    const int r0 = (rem >> 5) << 5, c0 = (rem & 31) << 5;
    const int tx = threadIdx.x & 31, ty = threadIdx.x >> 5;  // 32 x 8
#pragma unroll
    for (int rr = ty; rr < 32; rr += 8) t[rr][tx] = in[(size_t)(r0 + rr) * 1024 + c0 + tx];
    __syncthreads();
#pragma unroll
    for (int cc = ty; cc < 32; cc += 8)
      out[(size_t)(c0 + cc) * 1024 + r0 + tx] = f2bf(t[tx][cc]);
  } else {
    int i = (b - 4096) * 256 + threadIdx.x;
    const float* in;
    unsigned short* out;
    if (i < 1048576) { in = x; out = xb; }
    else { i -= 1048576; if (i >= 262144) return; in = out_w; out = OwB; }
    float4 v = ((const float4*)in)[i];
    u16x4 o;
    o.x = f2bf(v.x); o.y = f2bf(v.y); o.z = f2bf(v.z); o.w = f2bf(v.w);
    ((u16x4*)out)[i] = o;
  }
}

// ---------- bf16 GEMM 128x128, dbuf + 1 barrier/K-step (T3-min) ----------
// MODE 0: fp32 C.  MODE 1: bf16 C.  MODE 2: bf16 C for n0<VCOL0; cols >= VCOL0
// are written TRANSPOSED to VT[col-VCOL0][rowPerm] (fused V-transpose, with the
// per-64-tile kv permutation kvpos = ks*32 + krow*8 + e*4 + r so flash PV reads
// are single b128 under the shared k-slot perm pi).
template <int MODE>
__global__ __launch_bounds__(256)
void k_gemm_bt(const unsigned short* __restrict__ A, const unsigned short* __restrict__ BT,
               void* __restrict__ C, unsigned short* __restrict__ VT,
               int M, int N, int K) {
  const int VCOL0 = 2048;
  __shared__ __align__(16) unsigned short As[2][128 * 32];
  __shared__ __align__(16) unsigned short Bs[2][128 * 32];
  const int tid = threadIdx.x;
  const int wid = tid >> 6, lane = tid & 63;
  const int l16 = lane & 15, krow = lane >> 4;
  const int m0 = blockIdx.x * 128, n0 = blockIdx.y * 128;
  const int wr = wid >> 1, wc = wid & 1;  // 2x2 waves, 64x64 each

  f32x4 acc[4][4] = {};

  auto stageG = [&](int buf, int k0) {
#pragma unroll
    for (int j = 0; j < 2; j++) {
      int f = j * 256 + tid;
      gload_lds16(A  + (size_t)(m0 + (f >> 2)) * K + k0 + (f & 3) * 8,
                  (char*)As[buf] + (size_t)(j * 256 + wid * 64) * 16);
      gload_lds16(BT + (size_t)(n0 + (f >> 2)) * K + k0 + (f & 3) * 8,
                  (char*)Bs[buf] + (size_t)(j * 256 + wid * 64) * 16);
    }
  };
  auto comp = [&](int buf) {
    bf16x8 a[4], b[4];
#pragma unroll
    for (int i = 0; i < 4; i++) {
      a[i] = *(const bf16x8*)&As[buf][(wr * 64 + i * 16 + l16) * 32 + krow * 8];
      b[i] = *(const bf16x8*)&Bs[buf][(wc * 64 + i * 16 + l16) * 32 + krow * 8];
    }
#pragma unroll
    for (int mi = 0; mi < 4; mi++)
#pragma unroll
      for (int ni = 0; ni < 4; ni++)
        acc[mi][ni] = __builtin_amdgcn_mfma_f32_16x16x32_bf16(a[mi], b[ni], acc[mi][ni], 0, 0, 0);
  };

  stageG(0, 0);
  __syncthreads();
  for (int k0 = 0; k0 < K; k0 += 64) {
    if (k0 + 32 < K) stageG(1, k0 + 32);
    comp(0);
    __syncthreads();
    if (k0 + 64 < K) stageG(0, k0 + 64);
    comp(1);
    __syncthreads();
  }

  if (MODE == 2 && n0 >= VCOL0) {
    // V region: write transposed to VT[col - VCOL0][rowPerm]; rows consecutive per
    // lane (r=0..3) stay contiguous under the kv permutation (r bits unchanged).
#pragma unroll
    for (int mi = 0; mi < 4; mi++)
#pragma unroll
      for (int ni = 0; ni < 4; ni++) {
        int col = n0 - VCOL0 + wc * 64 + ni * 16 + l16;
        int row = m0 + wr * 64 + mi * 16 + krow * 4;
        int u0 = row & 63;
        int rowp = (row & ~63) | (u0 & 32) | ((u0 & 12) << 1) | (((u0 >> 4) & 1) << 2);
        uint2 w;
        w.x = (unsigned)f2bf(acc[mi][ni][0]) | ((unsigned)f2bf(acc[mi][ni][1]) << 16);
        w.y = (unsigned)f2bf(acc[mi][ni][2]) | ((unsigned)f2bf(acc[mi][ni][3]) << 16);
        *(uint2*)&VT[(size_t)col * 4096 + rowp] = w;
      }
    return;
  }

#pragma unroll
  for (int mi = 0; mi < 4; mi++)
#pragma unroll
    for (int ni = 0; ni < 4; ni++)
#pragma unroll
      for (int r = 0; r < 4; r++) {
        int row = m0 + wr * 64 + mi * 16 + krow * 4 + r;
        int col = n0 + wc * 64 + ni * 16 + l16;
        float v = acc[mi][ni][r];
        if (MODE) ((unsigned short*)C)[(size_t)row * N + col] = f2bf(v);
        else      ((float*)C)[(size_t)row * N + col] = v;
      }
}

// ---------- bf16 GEMM 128x64, dbuf + 1 barrier/K-step ----------
template <int OUTBF>
__global__ __launch_bounds__(256)
void k_gemm_bt_n64(const unsigned short* __restrict__ A, const unsigned short* __restrict__ BT,
                   void* __restrict__ C, int M, int N, int K) {
  __shared__ __align__(16) unsigned short As[2][128 * 32];
  __shared__ __align__(16) unsigned short Bs[2][64 * 32];
  const int tid = threadIdx.x;
  const int wid = tid >> 6, lane = tid & 63;
  const int l16 = lane & 15, krow = lane >> 4;
  const int m0 = blockIdx.x * 128, n0 = blockIdx.y * 64;
  const int wr = wid >> 1, wc = wid & 1;  // 2x2 waves, 64x32 each

  f32x4 acc[4][2] = {};

  auto stageG = [&](int buf, int k0) {
#pragma unroll
    for (int j = 0; j < 2; j++) {
      int f = j * 256 + tid;
      gload_lds16(A + (size_t)(m0 + (f >> 2)) * K + k0 + (f & 3) * 8,
                  (char*)As[buf] + (size_t)(j * 256 + wid * 64) * 16);
    }
    gload_lds16(BT + (size_t)(n0 + (tid >> 2)) * K + k0 + (tid & 3) * 8,
                (char*)Bs[buf] + (size_t)(wid * 64) * 16);
  };
  auto comp = [&](int buf) {
    bf16x8 a[4], b[2];
#pragma unroll
    for (int i = 0; i < 4; i++)
      a[i] = *(const bf16x8*)&As[buf][(wr * 64 + i * 16 + l16) * 32 + krow * 8];
#pragma unroll
    for (int i = 0; i < 2; i++)
      b[i] = *(const bf16x8*)&Bs[buf][(wc * 32 + i * 16 + l16) * 32 + krow * 8];
#pragma unroll
    for (int mi = 0; mi < 4; mi++)
#pragma unroll
      for (int ni = 0; ni < 2; ni++)
        acc[mi][ni] = __builtin_amdgcn_mfma_f32_16x16x32_bf16(a[mi], b[ni], acc[mi][ni], 0, 0, 0);
  };

  stageG(0, 0);
  __syncthreads();
  for (int k0 = 0; k0 < K; k0 += 64) {
    if (k0 + 32 < K) stageG(1, k0 + 32);
    comp(0);
    __syncthreads();
    if (k0 + 64 < K) stageG(0, k0 + 64);
    comp(1);
    __syncthreads();
  }

#pragma unroll
  for (int mi = 0; mi < 4; mi++)
#pragma unroll
    for (int ni = 0; ni < 2; ni++)
#pragma unroll
      for (int r = 0; r < 4; r++) {
        int row = m0 + wr * 64 + mi * 16 + krow * 4 + r;
        int col = n0 + wc * 32 + ni * 16 + l16;
        float v = acc[mi][ni][r];
        if (OUTBF) ((unsigned short*)C)[(size_t)row * N + col] = f2bf(v);
        else       ((float*)C)[(size_t)row * N + col] = v;
      }
}

// ---------- flash attention (R16 pipeline + b128 PV via permuted Vt) ----------
// 8 waves/WG (512 thr), 128 q-rows/WG, 16 q-rows/wave, grid 512 (16 heads x 32 qb).
// LDS 64 KB: 4 slots x (K 8KB | V 8KB) -> 2 WG/CU = 16 waves/CU. Prefetch depth 3,
// counted vmcnt(4) barriers (T4). Vt is kv-permuted by GEMM1 so the PV V A-frag
// is a SINGLE ds_read_b128 at koff+8192 (same address form as the K reads).
__global__ __launch_bounds__(512)
void k_flash(const unsigned short* __restrict__ QKV, const unsigned short* __restrict__ Vt,
             unsigned short* __restrict__ ctx) {
  // shorts: 4 slots x 8192 (K 4096 | V 4096 each)
  __shared__ __align__(16) unsigned short LDS[32768];
  const int tid = threadIdx.x, wid = tid >> 6, lane = tid & 63;
  const int l16 = lane & 15, krow = lane >> 4;
  const int bid = blockIdx.x;
  const int swz = (bid & 7) * 64 + (bid >> 3);    // 512 % 8 == 0 -> bijective
  const int head = swz >> 5, qb = swz & 31;       // 2 heads per XCD (K/V/Q ~3MB < 4MB L2)
  const float SC = 0.125f * 1.44269504089f;       // scale into log2 domain

  // Q fragments (B-operand of swapped QK^T): lane holds q-row l16, d = ks*32+krow*8..+7
  bf16x8 qf[2];
#pragma unroll
  for (int ks = 0; ks < 2; ks++) {
    int row = qb * 128 + wid * 16 + l16;
    qf[ks] = *(const bf16x8*)&QKV[(size_t)row * 3072 + head * 64 + ks * 32 + krow * 8];
  }

  // hoisted LDS byte offsets (slot 0; other slots via literal +16384k).
  // V reads use koff + 8192 (identical address form; Vt pre-permuted).
  unsigned koff[2][4];
#pragma unroll
  for (int ks = 0; ks < 2; ks++)
#pragma unroll
    for (int ni = 0; ni < 4; ni++) {
      int row = ni * 16 + l16;
      koff[ks][ni] = row * 128 + (((ks * 4 + krow) ^ (row & 7)) << 4);
    }

  // staging source cursors (advance once per staged tile) + fixed LDS dests
  const unsigned short* kSrc;
  const unsigned short* vSrc;
  {
    int row = tid >> 3, sch = (tid & 7) ^ (row & 7);  // pre-swizzled source
    kSrc = QKV + (size_t)row * 3072 + 1024 + head * 64 + sch * 8;
    vSrc = Vt + (size_t)(head * 64 + row) * 4096 + sch * 8;
  }
  char* dK = (char*)LDS + wid * 1024;           // + lane*16 by HW
  char* dV = (char*)LDS + 8192 + wid * 1024;

  f32x4 oaccT[4] = {};      // O^T tiles [di]; col=q(l16), row=d(krow*4+r)
  float mrun = -INFINITY;   // uniform across the 4 krow-lanes of a q
  float lrun = 0.f;         // PER-LANE partial (reduced in epilogue)

  auto stage = [&](const int B) {   // B = slot byte offset, literal
    gload_lds16(kSrc, dK + B);
    gload_lds16(vSrc, dV + B);
    kSrc += 64 * 3072;
    vSrc += 64;
  };

  auto body = [&](const int B) {  // B = slot byte offset, literal
    const char* L = (const char*)LDS;

    // swapped QK^T: sacc[ni] = S^T tile [kv 16][q 16]; lane owns q=l16, kv=ni*16+krow*4+r
    f32x4 sacc[4] = {};
    __builtin_amdgcn_s_setprio(1);
#pragma unroll
    for (int ks = 0; ks < 2; ks++)
#pragma unroll
      for (int ni = 0; ni < 4; ni++) {
        bf16x8 kf = *(const bf16x8*)(L + B + koff[ks][ni]);
        sacc[ni] = __builtin_amdgcn_mfma_f32_16x16x32_bf16(kf, qf[ks], sacc[ni], 0, 0, 0);
      }
    __builtin_amdgcn_s_setprio(0);

    // per-lane partial max over this lane's 16 kv values (raw domain)
    float a = fmax3(sacc[0][0], sacc[0][1], sacc[0][2]);
    a = fmax3(a, sacc[0][3], sacc[1][0]);
    a = fmax3(a, sacc[1][1], sacc[1][2]);
    a = fmax3(a, sacc[1][3], sacc[2][0]);
    a = fmax3(a, sacc[2][1], sacc[2][2]);
    a = fmax3(a, sacc[2][3], sacc[3][0]);
    a = fmax3(a, sacc[3][1], sacc[3][2]);
    a = fmaxf(a, sacc[3][3]);

    // defer-max: cross-lane reduce + rescale only when some lane's partial
    // exceeds the running max by > 8 (log2 domain)
    if (__ballot(__builtin_fmaf(a, SC, -mrun) > 8.f)) {
      a = fmaxf(a, __shfl_xor(a, 16));
      a = fmaxf(a, __shfl_xor(a, 32));      // uniform per q now
      float mnew = fmaxf(mrun, a * SC);
      float al = __builtin_amdgcn_exp2f(mrun - mnew);
      lrun *= al;
      mrun = mnew;
#pragma unroll
      for (int di = 0; di < 4; di++)
#pragma unroll
        for (int r = 0; r < 4; r++) oaccT[di][r] *= al;
    }

    // P = exp2(s*SC - m); per-lane partial row-sum (tree-reduced add chain)
    float ps[4];
#pragma unroll
    for (int ni = 0; ni < 4; ni++) {
      float p0 = __builtin_amdgcn_exp2f(__builtin_fmaf(sacc[ni][0], SC, -mrun));
      float p1 = __builtin_amdgcn_exp2f(__builtin_fmaf(sacc[ni][1], SC, -mrun));
      float p2 = __builtin_amdgcn_exp2f(__builtin_fmaf(sacc[ni][2], SC, -mrun));
      float p3 = __builtin_amdgcn_exp2f(__builtin_fmaf(sacc[ni][3], SC, -mrun));
      sacc[ni][0] = p0; sacc[ni][1] = p1; sacc[ni][2] = p2; sacc[ni][3] = p3;
      ps[ni] = (p0 + p1) + (p2 + p3);
    }
    lrun += (ps[0] + ps[1]) + (ps[2] + ps[3]);

    // B-frags: P^T packed from this lane's OWN sacc under k-slot perm pi:
    //   pi(ks,krow,j) = (2ks + (j>>2))*16 + krow*4 + (j&3)
    union PB { unsigned int w[4]; bf16x8 v; };
    PB pb[2];
#pragma unroll
    for (int ks = 0; ks < 2; ks++) {
      pb[ks].w[0] = pack_trunc(sacc[2 * ks][0],     sacc[2 * ks][1]);
      pb[ks].w[1] = pack_trunc(sacc[2 * ks][2],     sacc[2 * ks][3]);
      pb[ks].w[2] = pack_trunc(sacc[2 * ks + 1][0], sacc[2 * ks + 1][1]);
      pb[ks].w[3] = pack_trunc(sacc[2 * ks + 1][2], sacc[2 * ks + 1][3]);
    }

    // O^T += V^T P^T: A-frag = ONE b128 (Vt pre-permuted; same pi as pb)
    __builtin_amdgcn_s_setprio(1);
#pragma unroll
    for (int ks = 0; ks < 2; ks++)
#pragma unroll
      for (int di = 0; di < 4; di++) {
        bf16x8 av = *(const bf16x8*)(L + B + 8192 + koff[ks][di]);
        oaccT[di] = __builtin_amdgcn_mfma_f32_16x16x32_bf16(av, pb[ks].v, oaccT[di], 0, 0, 0);
      }
    __builtin_amdgcn_s_setprio(0);
  };

  // prologue: stage tiles 0,1,2 into slots 0,1,2 (6 loads in flight; cursor-ordered)
  stage(0);
  stage(16384);
  stage(32768);

  // steps t=0..59 (15 x 4 unroll, literal slots). Invariant at step t: tiles
  // t,t+1,t+2 staged (6 outstanding; t's 2 loads oldest). vmcnt(4) retires t.
  for (int t = 0; t < 60; t += 4) {
    FSYNC("4"); stage(49152); body(0);      // body tile t   (slot 0), stage t+3 (slot 3)
    FSYNC("4"); stage(0);     body(16384);  // body tile t+1 (slot 1), stage t+4 (slot 0)
    FSYNC("4"); stage(16384); body(32768);  // body tile t+2 (slot 2), stage t+5 (slot 1)
    FSYNC("4"); stage(32768); body(49152);  // body tile t+3 (slot 3), stage t+6 (slot 2)
  }
  // tail t=60..63: stage tile 63 at t=60; drain 4 -> 4 -> 2 -> 0
  FSYNC("4"); stage(49152); body(0);        // t=60 (slot 0), stage 63 (slot 3)
  FSYNC("4"); body(16384);                  // t=61 (slot 1)
  FSYNC("2"); body(32768);                  // t=62 (slot 2)
  FSYNC("0"); body(49152);                  // t=63 (slot 3)

  // epilogue: reduce per-lane l partials across the 4 krow-lanes of each q,
  // then per-lane normalize + 8B packed stores
  float lr = lrun;
  lr += __shfl_xor(lr, 16);
  lr += __shfl_xor(lr, 32);
  float li = 1.0f / lr;
  int row = qb * 128 + wid * 16 + l16;
#pragma unroll
  for (int di = 0; di < 4; di++) {
    uint2 w;
    w.x = (unsigned)f2bf(oaccT[di][0] * li) | ((unsigned)f2bf(oaccT[di][1] * li) << 16);
    w.y = (unsigned)f2bf(oaccT[di][2] * li) | ((unsigned)f2bf(oaccT[di][3] * li) << 16);
    *(uint2*)&ctx[(size_t)row * 1024 + head * 64 + di * 16 + krow * 4] = w;
  }
}

// ---------- LN(x + proj_bf16) -> bf16 only ----------
__global__ __launch_bounds__(256)
void k_ln_res(const float* __restrict__ base, const unsigned short* __restrict__ add,
              const float* __restrict__ g, const float* __restrict__ bb,
              unsigned short* __restrict__ outb) {
  const int r = blockIdx.x, tid = threadIdx.x;
  float4 v = ((const float4*)(base + (size_t)r * 1024))[tid];
  {
    u16x4 w = ((const u16x4*)(add + (size_t)r * 1024))[tid];
    v.x += bf2f(w.x); v.y += bf2f(w.y); v.z += bf2f(w.z); v.w += bf2f(w.w);
  }
  float s1 = v.x + v.y + v.z + v.w;
  float s2 = v.x * v.x + v.y * v.y + v.z * v.z + v.w * v.w;
#pragma unroll
  for (int off = 32; off >= 1; off >>= 1) { s1 += __shfl_xor(s1, off); s2 += __shfl_xor(s2, off); }
  __shared__ float red[8];
  if ((tid & 63) == 0) { red[tid >> 6] = s1; red[4 + (tid >> 6)] = s2; }
  __syncthreads();
  s1 = red[0] + red[1] + red[2] + red[3];
  s2 = red[4] + red[5] + red[6] + red[7];
  const float mu = s1 * (1.0f / 1024.0f);
  const float var = s2 * (1.0f / 1024.0f) - mu * mu;
  const float rs = rsqrtf(var + 1e-5f);
  float4 gv = ((const float4*)g)[tid];
  float4 bv = ((const float4*)bb)[tid];
  u16x4 o;
  o.x = f2bf((v.x - mu) * rs * gv.x + bv.x);
  o.y = f2bf((v.y - mu) * rs * gv.y + bv.y);
  o.z = f2bf((v.z - mu) * rs * gv.z + bv.z);
  o.w = f2bf((v.w - mu) * rs * gv.w + bv.w);
  ((u16x4*)(outb + (size_t)r * 1024))[tid] = o;
}

// ---------- relu(LN(lin_bf16 + out_b + mha_bf16)) -> fp32 out ----------
__global__ __launch_bounds__(256)
void k_ln2(const unsigned short* __restrict__ lin, const unsigned short* __restrict__ mha,
           const float* __restrict__ ob, const float* __restrict__ g,
           const float* __restrict__ bb, float* __restrict__ out) {
  const int r = blockIdx.x, tid = threadIdx.x;
  float4 v;
  {
    u16x4 a = ((const u16x4*)(lin + (size_t)r * 1024))[tid];
    u16x4 w = ((const u16x4*)(mha + (size_t)r * 1024))[tid];
    float4 o = ((const float4*)ob)[tid];
    v.x = bf2f(a.x) + bf2f(w.x) + o.x;
    v.y = bf2f(a.y) + bf2f(w.y) + o.y;
    v.z = bf2f(a.z) + bf2f(w.z) + o.z;
    v.w = bf2f(a.w) + bf2f(w.w) + o.w;
  }
  float s1 = v.x + v.y + v.z + v.w;
  float s2 = v.x * v.x + v.y * v.y + v.z * v.z + v.w * v.w;
#pragma unroll
  for (int off = 32; off >= 1; off >>= 1) { s1 += __shfl_xor(s1, off); s2 += __shfl_xor(s2, off); }
  __shared__ float red[8];
  if ((tid & 63) == 0) { red[tid >> 6] = s1; red[4 + (tid >> 6)] = s2; }
  __syncthreads();
  s1 = red[0] + red[1] + red[2] + red[3];
  s2 = red[4] + red[5] + red[6] + red[7];
  const float mu = s1 * (1.0f / 1024.0f);
  const float var = s2 * (1.0f / 1024.0f) - mu * mu;
  const float rs = rsqrtf(var + 1e-5f);
  float4 gv = ((const float4*)g)[tid];
  float4 bv = ((const float4*)bb)[tid];
  float4 y;
  y.x = fmaxf(0.f, (v.x - mu) * rs * gv.x + bv.x);
  y.y = fmaxf(0.f, (v.y - mu) * rs * gv.y + bv.y);
  y.z = fmaxf(0.f, (v.z - mu) * rs * gv.z + bv.z);
  y.w = fmaxf(0.f, (v.w - mu) * rs * gv.w + bv.w);
  ((float4*)(out + (size_t)r * 1024))[tid] = y;
}

// ---------- launch ----------
extern "C" void kernel_launch(void* const* d_in, const int* in_sizes, int n_in,
                              void* d_out, int out_size, void* d_ws, size_t ws_size,
                              hipStream_t stream) {
  (void)in_sizes; (void)n_in; (void)out_size; (void)ws_size;
  const float* x     = (const float*)d_in[0];
  const float* Wq    = (const float*)d_in[1];
  const float* Wk    = (const float*)d_in[2];
  const float* Wv    = (const float*)d_in[3];
  const float* Wo    = (const float*)d_in[4];
  const float* out_w = (const float*)d_in[5];
  const float* out_b = (const float*)d_in[6];
  const float* g1    = (const float*)d_in[7];
  const float* b1    = (const float*)d_in[8];
  const float* g2    = (const float*)d_in[9];
  const float* b2    = (const float*)d_in[10];
  float* out = (float*)d_out;

  // workspace layout (aliased; 60 MB total, liveness-checked)
  const size_t MB = 1ull << 20;
  char* ws = (char*)d_ws;
  unsigned short* xb    = (unsigned short*)(ws + 0);        // [4096][1024] bf16   (dead after GEMM1)
  unsigned short* WqkvT = (unsigned short*)(ws + 8 * MB);   // [3072][1024] bf16   (dead after GEMM1)
  unsigned short* OwB   = (unsigned short*)(ws + 16 * MB);  // out_w bf16 [1024][1024]
  unsigned short* QKV   = (unsigned short*)(ws + 18 * MB);  // [4096][3072] bf16 (Q,K used; V cols unwritten)
  unsigned short* Vt    = (unsigned short*)(ws + 42 * MB);  // [1024][4096] bf16 kv-permuted (dead after attn)
  unsigned short* ctx   = (unsigned short*)(ws + 50 * MB);  // [4096][1024] bf16   (dead after GEMM2)
  unsigned short* WoT   = (unsigned short*)(ws + 58 * MB);  // W_o^T bf16
  unsigned short* proj  = (unsigned short*)(ws + 0);        // [4096][1024] bf16 (over xb)
  unsigned short* mhaB  = (unsigned short*)(ws + 34 * MB);  // [4096][1024] bf16 (over QKV tail)
  unsigned short* lin   = (unsigned short*)(ws + 42 * MB);  // [4096][1024] bf16 (over Vt)

  k_prep<<<9216, 256, 0, stream>>>(x, xb, out_w, OwB, Wq, Wk, Wv, Wo, WqkvT, WoT);

  // GEMM1: QKV projection; V columns (n0>=2048) stream transposed+permuted into Vt
  k_gemm_bt<2><<<dim3(32, 24), 256, 0, stream>>>(xb, WqkvT, QKV, Vt, 4096, 3072, 1024);
  k_flash<<<512, 512, 0, stream>>>(QKV, Vt, ctx);
  k_gemm_bt_n64<1><<<dim3(32, 16), 256, 0, stream>>>(ctx, WoT, proj, 4096, 1024, 1024);
  k_ln_res<<<4096, 256, 0, stream>>>(x, proj, g1, b1, mhaB);
  k_gemm_bt_n64<1><<<dim3(32, 16), 256, 0, stream>>>(mhaB, OwB, lin, 4096, 1024, 1024);
  k_ln2<<<4096, 256, 0, stream>>>(lin, mhaB, out_b, g2, b2, out);
}